// Round 1
// baseline (192.754 us; speedup 1.0000x reference)
//
#include <hip/hip_runtime.h>
#include <hip/hip_bf16.h>
#include <stdint.h>

#define BATCH 2
#define SEQ   2048
#define HID   1024
#define NH    16
#define HD    64
#define W2    128   // WINDOW/2

using bhalf8 = __attribute__((ext_vector_type(8))) short;
using fvec4  = __attribute__((ext_vector_type(4))) float;
using u16x8  = __attribute__((ext_vector_type(8))) unsigned short;

__device__ __forceinline__ unsigned short f2bf(float f) {
    union { float f; unsigned int u; } c; c.f = f;
    unsigned int u = c.u;
    u += 0x7FFFu + ((u >> 16) & 1u);   // RNE
    return (unsigned short)(u >> 16);
}

__device__ __forceinline__ fvec4 zero4() {
    fvec4 z = {0.f, 0.f, 0.f, 0.f};
    return z;
}

__device__ __forceinline__ void load_lds16(const void* g, void* l) {
    __builtin_amdgcn_global_load_lds(
        (const __attribute__((address_space(1))) void*)g,
        (__attribute__((address_space(3))) void*)l, 16, 0, 0);
}

__device__ __forceinline__ float rowmax16(float v) {
    v = fmaxf(v, __shfl_xor(v, 1));
    v = fmaxf(v, __shfl_xor(v, 2));
    v = fmaxf(v, __shfl_xor(v, 4));
    v = fmaxf(v, __shfl_xor(v, 8));
    return v;
}
__device__ __forceinline__ float rowsum16(float v) {
    v += __shfl_xor(v, 1);
    v += __shfl_xor(v, 2);
    v += __shfl_xor(v, 4);
    v += __shfl_xor(v, 8);
    return v;
}

// ---------------- conversion kernels ----------------

__global__ __launch_bounds__(256) void k_convert_x(const float* __restrict__ x,
                                                   unsigned short* __restrict__ xb) {
    int i = (blockIdx.x * 256 + threadIdx.x) * 8;
    float4 a = *(const float4*)(x + i);
    float4 b = *(const float4*)(x + i + 4);
    u16x8 o;
    o[0] = f2bf(a.x); o[1] = f2bf(a.y); o[2] = f2bf(a.z); o[3] = f2bf(a.w);
    o[4] = f2bf(b.x); o[5] = f2bf(b.y); o[6] = f2bf(b.z); o[7] = f2bf(b.w);
    *(u16x8*)(xb + i) = o;
}

// transpose [K][N] fp32 -> [N][K] bf16, 32x32 tiles
__global__ __launch_bounds__(256) void k_transpose_w(
    const float* __restrict__ w0, const float* __restrict__ w1,
    const float* __restrict__ w2, const float* __restrict__ w3,
    unsigned short* __restrict__ t0, unsigned short* __restrict__ t1,
    unsigned short* __restrict__ t2, unsigned short* __restrict__ t3) {
    int z = blockIdx.z;
    const float* src = (z == 0) ? w0 : (z == 1) ? w1 : (z == 2) ? w2 : w3;
    unsigned short* dst = (z == 0) ? t0 : (z == 1) ? t1 : (z == 2) ? t2 : t3;
    __shared__ float tile[32][33];
    int n0 = blockIdx.x * 32, k0 = blockIdx.y * 32;
    int tx = threadIdx.x, ty = threadIdx.y;
#pragma unroll
    for (int r = 0; r < 4; ++r)
        tile[ty + 8 * r][tx] = src[(size_t)(k0 + ty + 8 * r) * HID + n0 + tx];
    __syncthreads();
#pragma unroll
    for (int r = 0; r < 4; ++r)
        dst[(size_t)(n0 + ty + 8 * r) * HID + k0 + tx] = f2bf(tile[tx][ty + 8 * r]);
}

// ---------------- GEMM mainloop (m97-style, 128x128, BK=32) ----------------
// A: [M][1024] bf16 row-major; Bt: [N][1024] bf16 (weight transposed)
__device__ __forceinline__ void gemm_tile(const unsigned short* __restrict__ A,
                                          const unsigned short* __restrict__ Bt,
                                          int m0, int n0,
                                          unsigned short* As, unsigned short* Bs,
                                          fvec4 acc[4][4]) {
    const int t = threadIdx.x;
    const int lane = t & 63;
    const int wid = t >> 6;
    const int wr = wid >> 1, wc = wid & 1;
    const int c16 = lane & 15, g = lane >> 4;

#pragma unroll
    for (int mi = 0; mi < 4; ++mi)
#pragma unroll
        for (int ni = 0; ni < 4; ++ni) acc[mi][ni] = zero4();

    for (int k0 = 0; k0 < HID; k0 += 32) {
#pragma unroll
        for (int i = 0; i < 2; ++i) {
            int slot = t + 256 * i;
            int row = slot >> 2, ch = slot & 3;
            load_lds16(A + (size_t)(m0 + row) * HID + k0 + ch * 8, As + slot * 8);
        }
#pragma unroll
        for (int i = 0; i < 2; ++i) {
            int slot = t + 256 * i;
            int row = slot >> 2, ch = slot & 3;
            load_lds16(Bt + (size_t)(n0 + row) * HID + k0 + ch * 8, Bs + slot * 8);
        }
        asm volatile("s_waitcnt vmcnt(0)" ::: "memory");
        __syncthreads();

        const unsigned short* Ap = As + (wr * 64 + c16) * 32 + g * 8;
        const unsigned short* Bp = Bs + (wc * 64 + c16) * 32 + g * 8;
        bhalf8 af[4], bf[4];
#pragma unroll
        for (int i = 0; i < 4; ++i) {
            af[i] = *(const bhalf8*)(Ap + i * 16 * 32);
            bf[i] = *(const bhalf8*)(Bp + i * 16 * 32);
        }
#pragma unroll
        for (int mi = 0; mi < 4; ++mi)
#pragma unroll
            for (int ni = 0; ni < 4; ++ni)
                acc[mi][ni] = __builtin_amdgcn_mfma_f32_16x16x32_bf16(
                    af[mi], bf[ni], acc[mi][ni], 0, 0, 0);
        __syncthreads();
    }
}

// QKV projection: z=0 -> Q (scaled, [b,h,s,d]), z=1 -> K ([b,h,s,d]), z=2 -> V^T ([b,h,d,s])
__global__ __launch_bounds__(256) void k_gemm_qkv(
    const unsigned short* __restrict__ xb,
    const unsigned short* __restrict__ wqt, const unsigned short* __restrict__ wkt,
    const unsigned short* __restrict__ wvt,
    const float* __restrict__ bq, const float* __restrict__ bk, const float* __restrict__ bv,
    unsigned short* __restrict__ qb, unsigned short* __restrict__ kbuf,
    unsigned short* __restrict__ vt) {
    __shared__ unsigned short As[128 * 32];
    __shared__ unsigned short Bs[128 * 32];
    const int z = blockIdx.z;
    const unsigned short* Bt = (z == 0) ? wqt : (z == 1) ? wkt : wvt;
    const float* bias = (z == 0) ? bq : (z == 1) ? bk : bv;
    const int m0 = blockIdx.y * 128, n0 = blockIdx.x * 128;
    fvec4 acc[4][4];
    gemm_tile(xb, Bt, m0, n0, As, Bs, acc);

    const int lane = threadIdx.x & 63, wid = threadIdx.x >> 6;
    const int wr = wid >> 1, wc = wid & 1, c16 = lane & 15, g = lane >> 4;
#pragma unroll
    for (int mi = 0; mi < 4; ++mi) {
#pragma unroll
        for (int ni = 0; ni < 4; ++ni) {
            int gcol = n0 + wc * 64 + ni * 16 + c16;
            int h = gcol >> 6, d = gcol & 63;
            float bsv = bias[gcol];
#pragma unroll
            for (int r = 0; r < 4; ++r) {
                int grow = m0 + wr * 64 + mi * 16 + 4 * g + r;
                int b = grow >> 11, s = grow & (SEQ - 1);
                float v = acc[mi][ni][r] + bsv;
                if (z == 0)
                    qb[((size_t)(b * NH + h) * SEQ + s) * HD + d] = f2bf(v * 0.125f);
                else if (z == 1)
                    kbuf[((size_t)(b * NH + h) * SEQ + s) * HD + d] = f2bf(v);
                else
                    vt[((size_t)(b * NH + h) * HD + d) * SEQ + s] = f2bf(v);
            }
        }
    }
}

// Output projection -> fp32 out
__global__ __launch_bounds__(256) void k_gemm_out(
    const unsigned short* __restrict__ attn, const unsigned short* __restrict__ wot,
    const float* __restrict__ bo, float* __restrict__ out) {
    __shared__ unsigned short As[128 * 32];
    __shared__ unsigned short Bs[128 * 32];
    const int m0 = blockIdx.y * 128, n0 = blockIdx.x * 128;
    fvec4 acc[4][4];
    gemm_tile(attn, wot, m0, n0, As, Bs, acc);

    const int lane = threadIdx.x & 63, wid = threadIdx.x >> 6;
    const int wr = wid >> 1, wc = wid & 1, c16 = lane & 15, g = lane >> 4;
#pragma unroll
    for (int mi = 0; mi < 4; ++mi) {
#pragma unroll
        for (int ni = 0; ni < 4; ++ni) {
            int gcol = n0 + wc * 64 + ni * 16 + c16;
            float bsv = bo[gcol];
#pragma unroll
            for (int r = 0; r < 4; ++r) {
                int grow = m0 + wr * 64 + mi * 16 + 4 * g + r;
                out[(size_t)grow * HID + gcol] = acc[mi][ni][r] + bsv;
            }
        }
    }
}

// ---------------- windowed flash attention ----------------
// grid: (SEQ/64, BATCH*NH), block 256. Each wave: 16 query rows.
__global__ __launch_bounds__(256) void k_attn(
    const unsigned short* __restrict__ qb, const unsigned short* __restrict__ kbuf,
    const unsigned short* __restrict__ vt, unsigned short* __restrict__ attn) {
    const int bh = blockIdx.y;
    const int wid = threadIdx.x >> 6, lane = threadIdx.x & 63;
    const int g = lane >> 4, c16 = lane & 15;
    const int q0 = blockIdx.x * 64 + wid * 16;

    const unsigned short* Qp = qb + (size_t)bh * SEQ * HD;
    const unsigned short* Kp = kbuf + (size_t)bh * SEQ * HD;
    const unsigned short* Vp = vt + (size_t)bh * HD * SEQ;

    __shared__ unsigned short Plds[4][16 * 32];
    unsigned short* myP = Plds[wid];

    bhalf8 qf0, qf1;
    {
        const unsigned short* p = Qp + (size_t)(q0 + c16) * HD + g * 8;
        qf0 = *(const bhalf8*)p;
        qf1 = *(const bhalf8*)(p + 32);
    }
    fvec4 acc[4];
#pragma unroll
    for (int i = 0; i < 4; ++i) acc[i] = zero4();
    float mrow[4] = {-1e30f, -1e30f, -1e30f, -1e30f};
    float srow[4] = {0.f, 0.f, 0.f, 0.f};

    int kstart = q0 - W2; if (kstart < 0) kstart = 0; kstart &= ~31;
    int kend = q0 + 15 + W2; if (kend > SEQ - 1) kend = SEQ - 1;

    for (int t0 = kstart; t0 <= kend; t0 += 32) {
        fvec4 sc0 = zero4(), sc1 = zero4();
        {
            const unsigned short* kp = Kp + (size_t)(t0 + c16) * HD + g * 8;
            bhalf8 ka = *(const bhalf8*)kp;
            bhalf8 kb2 = *(const bhalf8*)(kp + 32);
            sc0 = __builtin_amdgcn_mfma_f32_16x16x32_bf16(qf0, ka, sc0, 0, 0, 0);
            sc0 = __builtin_amdgcn_mfma_f32_16x16x32_bf16(qf1, kb2, sc0, 0, 0, 0);
        }
        {
            const unsigned short* kp = Kp + (size_t)(t0 + 16 + c16) * HD + g * 8;
            bhalf8 ka = *(const bhalf8*)kp;
            bhalf8 kb2 = *(const bhalf8*)(kp + 32);
            sc1 = __builtin_amdgcn_mfma_f32_16x16x32_bf16(qf0, ka, sc1, 0, 0, 0);
            sc1 = __builtin_amdgcn_mfma_f32_16x16x32_bf16(qf1, kb2, sc1, 0, 0, 0);
        }
        // band mask
#pragma unroll
        for (int r = 0; r < 4; ++r) {
            int ia = q0 + 4 * g + r;
            int j0 = t0 + c16, j1 = t0 + 16 + c16;
            if (j0 < ia - W2 || j0 > ia + W2) sc0[r] = -1e30f;
            if (j1 < ia - W2 || j1 > ia + W2) sc1[r] = -1e30f;
        }
        // online softmax update
#pragma unroll
        for (int r = 0; r < 4; ++r) {
            float pm = rowmax16(fmaxf(sc0[r], sc1[r]));
            float mn = fmaxf(mrow[r], pm);
            float f = __expf(mrow[r] - mn);
            mrow[r] = mn;
            float p0 = __expf(sc0[r] - mn);
            float p1 = __expf(sc1[r] - mn);
            srow[r] = srow[r] * f + (p0 + p1);   // per-lane partial; reduced at end
#pragma unroll
            for (int db = 0; db < 4; ++db) acc[db][r] *= f;
            myP[(4 * g + r) * 32 + c16] = f2bf(p0);
            myP[(4 * g + r) * 32 + 16 + c16] = f2bf(p1);
        }
        asm volatile("s_waitcnt lgkmcnt(0)" ::: "memory");
        __builtin_amdgcn_sched_barrier(0);
        bhalf8 pf = *(const bhalf8*)(myP + c16 * 32 + g * 8);
#pragma unroll
        for (int db = 0; db < 4; ++db) {
            const unsigned short* vp = Vp + (size_t)(db * 16 + c16) * SEQ + t0 + g * 8;
            bhalf8 vf = *(const bhalf8*)vp;
            acc[db] = __builtin_amdgcn_mfma_f32_16x16x32_bf16(pf, vf, acc[db], 0, 0, 0);
        }
    }

    float inv[4];
#pragma unroll
    for (int r = 0; r < 4; ++r) inv[r] = 1.f / rowsum16(srow[r]);

    const int b = bh >> 4, h = bh & 15;
#pragma unroll
    for (int db = 0; db < 4; ++db)
#pragma unroll
        for (int r = 0; r < 4; ++r) {
            int si = q0 + 4 * g + r;
            attn[((size_t)(b * SEQ) + si) * HID + h * HD + db * 16 + c16] =
                f2bf(acc[db][r] * inv[r]);
        }
}

// ---------------- launch ----------------

extern "C" void kernel_launch(void* const* d_in, const int* in_sizes, int n_in,
                              void* d_out, int out_size, void* d_ws, size_t ws_size,
                              hipStream_t stream) {
    const float* x  = (const float*)d_in[0];
    const float* wq = (const float*)d_in[1];
    const float* bq = (const float*)d_in[2];
    const float* wk = (const float*)d_in[3];
    const float* bk = (const float*)d_in[4];
    const float* wv = (const float*)d_in[5];
    const float* bv = (const float*)d_in[6];
    const float* wo = (const float*)d_in[7];
    const float* bo = (const float*)d_in[8];
    float* out = (float*)d_out;

    char* ws = (char*)d_ws;
    // layout (bytes): xb 8MB | wqt,wkt,wvt,wot 2MB each | qb 8MB | kb 8MB | vt 8MB | attn 8MB
    unsigned short* xb   = (unsigned short*)(ws);
    unsigned short* wqt  = (unsigned short*)(ws + (8u << 20));
    unsigned short* wkt  = wqt + 1024 * 1024;
    unsigned short* wvt  = wkt + 1024 * 1024;
    unsigned short* wot  = wvt + 1024 * 1024;
    unsigned short* qb   = wot + 1024 * 1024;
    unsigned short* kbuf = qb + 4u * 1024 * 1024;
    unsigned short* vt   = kbuf + 4u * 1024 * 1024;
    unsigned short* attn = vt + 4u * 1024 * 1024;

    k_convert_x<<<dim3(2048), dim3(256), 0, stream>>>(x, xb);
    k_transpose_w<<<dim3(32, 32, 4), dim3(32, 8), 0, stream>>>(wq, wk, wv, wo,
                                                               wqt, wkt, wvt, wot);
    k_gemm_qkv<<<dim3(8, 32, 3), dim3(256), 0, stream>>>(xb, wqt, wkt, wvt,
                                                         bq, bk, bv, qb, kbuf, vt);
    k_attn<<<dim3(SEQ / 64, BATCH * NH), dim3(256), 0, stream>>>(qb, kbuf, vt, attn);
    k_gemm_out<<<dim3(8, 32), dim3(256), 0, stream>>>(attn, wot, bo, out);
}

// Round 4
// 192.080 us; speedup vs baseline: 1.0035x; 1.0035x over previous
//
#include <hip/hip_runtime.h>
#include <hip/hip_bf16.h>
#include <stdint.h>

#define BATCH 2
#define SEQ   2048
#define HID   1024
#define NH    16
#define HD    64
#define W2    128   // WINDOW/2

using bhalf8 = __attribute__((ext_vector_type(8))) short;
using fvec4  = __attribute__((ext_vector_type(4))) float;
using u16x8  = __attribute__((ext_vector_type(8))) unsigned short;

__device__ __forceinline__ unsigned short f2bf(float f) {
    union { float f; unsigned int u; } c; c.f = f;
    unsigned int u = c.u;
    u += 0x7FFFu + ((u >> 16) & 1u);   // RNE
    return (unsigned short)(u >> 16);
}

__device__ __forceinline__ fvec4 zero4() {
    fvec4 z = {0.f, 0.f, 0.f, 0.f};
    return z;
}

__device__ __forceinline__ void load_lds16(const void* g, void* l) {
    __builtin_amdgcn_global_load_lds(
        (const __attribute__((address_space(1))) void*)g,
        (__attribute__((address_space(3))) void*)l, 16, 0, 0);
}

__device__ __forceinline__ float rowmax16(float v) {
    v = fmaxf(v, __shfl_xor(v, 1));
    v = fmaxf(v, __shfl_xor(v, 2));
    v = fmaxf(v, __shfl_xor(v, 4));
    v = fmaxf(v, __shfl_xor(v, 8));
    return v;
}
__device__ __forceinline__ float rowsum16(float v) {
    v += __shfl_xor(v, 1);
    v += __shfl_xor(v, 2);
    v += __shfl_xor(v, 4);
    v += __shfl_xor(v, 8);
    return v;
}

// ---------------- conversion kernels ----------------

__global__ __launch_bounds__(256) void k_convert_x(const float* __restrict__ x,
                                                   unsigned short* __restrict__ xb) {
    int i = (blockIdx.x * 256 + threadIdx.x) * 8;
    float4 a = *(const float4*)(x + i);
    float4 b = *(const float4*)(x + i + 4);
    u16x8 o;
    o[0] = f2bf(a.x); o[1] = f2bf(a.y); o[2] = f2bf(a.z); o[3] = f2bf(a.w);
    o[4] = f2bf(b.x); o[5] = f2bf(b.y); o[6] = f2bf(b.z); o[7] = f2bf(b.w);
    *(u16x8*)(xb + i) = o;
}

// transpose [K][N] fp32 -> [N][K] bf16, 32x32 tiles
__global__ __launch_bounds__(256) void k_transpose_w(
    const float* __restrict__ w0, const float* __restrict__ w1,
    const float* __restrict__ w2, const float* __restrict__ w3,
    unsigned short* __restrict__ t0, unsigned short* __restrict__ t1,
    unsigned short* __restrict__ t2, unsigned short* __restrict__ t3) {
    int z = blockIdx.z;
    const float* src = (z == 0) ? w0 : (z == 1) ? w1 : (z == 2) ? w2 : w3;
    unsigned short* dst = (z == 0) ? t0 : (z == 1) ? t1 : (z == 2) ? t2 : t3;
    __shared__ float tile[32][33];
    int n0 = blockIdx.x * 32, k0 = blockIdx.y * 32;
    int tx = threadIdx.x, ty = threadIdx.y;
#pragma unroll
    for (int r = 0; r < 4; ++r)
        tile[ty + 8 * r][tx] = src[(size_t)(k0 + ty + 8 * r) * HID + n0 + tx];
    __syncthreads();
#pragma unroll
    for (int r = 0; r < 4; ++r)
        dst[(size_t)(n0 + ty + 8 * r) * HID + k0 + tx] = f2bf(tile[tx][ty + 8 * r]);
}

// ---------------- GEMM mainloop (2-phase double-buffered, 128x128, BK=32) ----
// A: [M][1024] bf16 row-major; Bt: [N][1024] bf16 (weight transposed)

__device__ __forceinline__ void stage_tile(const unsigned short* __restrict__ A,
                                           const unsigned short* __restrict__ Bt,
                                           int m0, int n0, int k0,
                                           unsigned short* As, unsigned short* Bs,
                                           int t) {
#pragma unroll
    for (int i = 0; i < 2; ++i) {
        int slot = t + 256 * i;
        int row = slot >> 2, ch = slot & 3;
        load_lds16(A + (size_t)(m0 + row) * HID + k0 + ch * 8, As + slot * 8);
    }
#pragma unroll
    for (int i = 0; i < 2; ++i) {
        int slot = t + 256 * i;
        int row = slot >> 2, ch = slot & 3;
        load_lds16(Bt + (size_t)(n0 + row) * HID + k0 + ch * 8, Bs + slot * 8);
    }
}

// As/Bs: two 128*32 bf16 buffers each (double-buffered K-tiles), 32 KB total.
// Schedule per K-step (T3 "minimum 2-phase"): barrier (drains prev staging +
// ds_reads) -> issue next-tile global_load_lds -> ds_read current -> MFMA.
// Staging latency hides under the current tile's compute.
__device__ __forceinline__ void gemm_tile(const unsigned short* __restrict__ A,
                                          const unsigned short* __restrict__ Bt,
                                          int m0, int n0,
                                          unsigned short (*As)[128 * 32],
                                          unsigned short (*Bs)[128 * 32],
                                          fvec4 acc[4][4]) {
    const int t = threadIdx.x;
    const int lane = t & 63;
    const int wid = t >> 6;
    const int wr = wid >> 1, wc = wid & 1;
    const int c16 = lane & 15, g = lane >> 4;

#pragma unroll
    for (int mi = 0; mi < 4; ++mi)
#pragma unroll
        for (int ni = 0; ni < 4; ++ni) acc[mi][ni] = zero4();

    stage_tile(A, Bt, m0, n0, 0, As[0], Bs[0], t);

    int cur = 0;
    for (int k0 = 0; k0 < HID; k0 += 32) {
        __syncthreads();   // staging for buf[cur] complete; prev reads drained
        if (k0 + 32 < HID)
            stage_tile(A, Bt, m0, n0, k0 + 32, As[cur ^ 1], Bs[cur ^ 1], t);

        const unsigned short* Ap = As[cur] + (wr * 64 + c16) * 32 + g * 8;
        const unsigned short* Bp = Bs[cur] + (wc * 64 + c16) * 32 + g * 8;
        bhalf8 af[4], bf[4];
#pragma unroll
        for (int i = 0; i < 4; ++i) {
            af[i] = *(const bhalf8*)(Ap + i * 16 * 32);
            bf[i] = *(const bhalf8*)(Bp + i * 16 * 32);
        }
#pragma unroll
        for (int mi = 0; mi < 4; ++mi)
#pragma unroll
            for (int ni = 0; ni < 4; ++ni)
                acc[mi][ni] = __builtin_amdgcn_mfma_f32_16x16x32_bf16(
                    af[mi], bf[ni], acc[mi][ni], 0, 0, 0);
        cur ^= 1;
    }
}

// QKV projection: z=0 -> Q (scaled, [b,h,s,d]), z=1 -> K ([b,h,s,d]), z=2 -> V^T ([b,h,d,s])
__global__ __launch_bounds__(256) void k_gemm_qkv(
    const unsigned short* __restrict__ xb,
    const unsigned short* __restrict__ wqt, const unsigned short* __restrict__ wkt,
    const unsigned short* __restrict__ wvt,
    const float* __restrict__ bq, const float* __restrict__ bk, const float* __restrict__ bv,
    unsigned short* __restrict__ qb, unsigned short* __restrict__ kbuf,
    unsigned short* __restrict__ vt) {
    __shared__ unsigned short As[2][128 * 32];
    __shared__ unsigned short Bs[2][128 * 32];
    const int z = blockIdx.z;
    const unsigned short* Bt = (z == 0) ? wqt : (z == 1) ? wkt : wvt;
    const float* bias = (z == 0) ? bq : (z == 1) ? bk : bv;
    const int m0 = blockIdx.y * 128, n0 = blockIdx.x * 128;
    fvec4 acc[4][4];
    gemm_tile(xb, Bt, m0, n0, As, Bs, acc);

    const int lane = threadIdx.x & 63, wid = threadIdx.x >> 6;
    const int wr = wid >> 1, wc = wid & 1, c16 = lane & 15, g = lane >> 4;
#pragma unroll
    for (int mi = 0; mi < 4; ++mi) {
#pragma unroll
        for (int ni = 0; ni < 4; ++ni) {
            int gcol = n0 + wc * 64 + ni * 16 + c16;
            int h = gcol >> 6, d = gcol & 63;
            float bsv = bias[gcol];
#pragma unroll
            for (int r = 0; r < 4; ++r) {
                int grow = m0 + wr * 64 + mi * 16 + 4 * g + r;
                int b = grow >> 11, s = grow & (SEQ - 1);
                float v = acc[mi][ni][r] + bsv;
                if (z == 0)
                    qb[((size_t)(b * NH + h) * SEQ + s) * HD + d] = f2bf(v * 0.125f);
                else if (z == 1)
                    kbuf[((size_t)(b * NH + h) * SEQ + s) * HD + d] = f2bf(v);
                else
                    vt[((size_t)(b * NH + h) * HD + d) * SEQ + s] = f2bf(v);
            }
        }
    }
}

// Output projection -> fp32 out
__global__ __launch_bounds__(256) void k_gemm_out(
    const unsigned short* __restrict__ attn, const unsigned short* __restrict__ wot,
    const float* __restrict__ bo, float* __restrict__ out) {
    __shared__ unsigned short As[2][128 * 32];
    __shared__ unsigned short Bs[2][128 * 32];
    const int m0 = blockIdx.y * 128, n0 = blockIdx.x * 128;
    fvec4 acc[4][4];
    gemm_tile(attn, wot, m0, n0, As, Bs, acc);

    const int lane = threadIdx.x & 63, wid = threadIdx.x >> 6;
    const int wr = wid >> 1, wc = wid & 1, c16 = lane & 15, g = lane >> 4;
#pragma unroll
    for (int mi = 0; mi < 4; ++mi) {
#pragma unroll
        for (int ni = 0; ni < 4; ++ni) {
            int gcol = n0 + wc * 64 + ni * 16 + c16;
            float bsv = bo[gcol];
#pragma unroll
            for (int r = 0; r < 4; ++r) {
                int grow = m0 + wr * 64 + mi * 16 + 4 * g + r;
                out[(size_t)grow * HID + gcol] = acc[mi][ni][r] + bsv;
            }
        }
    }
}

// ---------------- windowed flash attention ----------------
// grid: (SEQ/64, BATCH*NH), block 256. Each wave: 16 query rows.
__global__ __launch_bounds__(256) void k_attn(
    const unsigned short* __restrict__ qb, const unsigned short* __restrict__ kbuf,
    const unsigned short* __restrict__ vt, unsigned short* __restrict__ attn) {
    const int bh = blockIdx.y;
    const int wid = threadIdx.x >> 6, lane = threadIdx.x & 63;
    const int g = lane >> 4, c16 = lane & 15;
    const int q0 = blockIdx.x * 64 + wid * 16;

    const unsigned short* Qp = qb + (size_t)bh * SEQ * HD;
    const unsigned short* Kp = kbuf + (size_t)bh * SEQ * HD;
    const unsigned short* Vp = vt + (size_t)bh * HD * SEQ;

    __shared__ unsigned short Plds[4][16 * 32];
    unsigned short* myP = Plds[wid];

    bhalf8 qf0, qf1;
    {
        const unsigned short* p = Qp + (size_t)(q0 + c16) * HD + g * 8;
        qf0 = *(const bhalf8*)p;
        qf1 = *(const bhalf8*)(p + 32);
    }
    fvec4 acc[4];
#pragma unroll
    for (int i = 0; i < 4; ++i) acc[i] = zero4();
    float mrow[4] = {-1e30f, -1e30f, -1e30f, -1e30f};
    float srow[4] = {0.f, 0.f, 0.f, 0.f};

    int kstart = q0 - W2; if (kstart < 0) kstart = 0; kstart &= ~31;
    int kend = q0 + 15 + W2; if (kend > SEQ - 1) kend = SEQ - 1;

    for (int t0 = kstart; t0 <= kend; t0 += 32) {
        fvec4 sc0 = zero4(), sc1 = zero4();
        {
            const unsigned short* kp = Kp + (size_t)(t0 + c16) * HD + g * 8;
            bhalf8 ka = *(const bhalf8*)kp;
            bhalf8 kb2 = *(const bhalf8*)(kp + 32);
            sc0 = __builtin_amdgcn_mfma_f32_16x16x32_bf16(qf0, ka, sc0, 0, 0, 0);
            sc0 = __builtin_amdgcn_mfma_f32_16x16x32_bf16(qf1, kb2, sc0, 0, 0, 0);
        }
        {
            const unsigned short* kp = Kp + (size_t)(t0 + 16 + c16) * HD + g * 8;
            bhalf8 ka = *(const bhalf8*)kp;
            bhalf8 kb2 = *(const bhalf8*)(kp + 32);
            sc1 = __builtin_amdgcn_mfma_f32_16x16x32_bf16(qf0, ka, sc1, 0, 0, 0);
            sc1 = __builtin_amdgcn_mfma_f32_16x16x32_bf16(qf1, kb2, sc1, 0, 0, 0);
        }
        // band mask
#pragma unroll
        for (int r = 0; r < 4; ++r) {
            int ia = q0 + 4 * g + r;
            int j0 = t0 + c16, j1 = t0 + 16 + c16;
            if (j0 < ia - W2 || j0 > ia + W2) sc0[r] = -1e30f;
            if (j1 < ia - W2 || j1 > ia + W2) sc1[r] = -1e30f;
        }
        // online softmax update
#pragma unroll
        for (int r = 0; r < 4; ++r) {
            float pm = rowmax16(fmaxf(sc0[r], sc1[r]));
            float mn = fmaxf(mrow[r], pm);
            float f = __expf(mrow[r] - mn);
            mrow[r] = mn;
            float p0 = __expf(sc0[r] - mn);
            float p1 = __expf(sc1[r] - mn);
            srow[r] = srow[r] * f + (p0 + p1);   // per-lane partial; reduced at end
#pragma unroll
            for (int db = 0; db < 4; ++db) acc[db][r] *= f;
            myP[(4 * g + r) * 32 + c16] = f2bf(p0);
            myP[(4 * g + r) * 32 + 16 + c16] = f2bf(p1);
        }
        asm volatile("s_waitcnt lgkmcnt(0)" ::: "memory");
        __builtin_amdgcn_sched_barrier(0);
        bhalf8 pf = *(const bhalf8*)(myP + c16 * 32 + g * 8);
#pragma unroll
        for (int db = 0; db < 4; ++db) {
            const unsigned short* vp = Vp + (size_t)(db * 16 + c16) * SEQ + t0 + g * 8;
            bhalf8 vf = *(const bhalf8*)vp;
            acc[db] = __builtin_amdgcn_mfma_f32_16x16x32_bf16(pf, vf, acc[db], 0, 0, 0);
        }
    }

    float inv[4];
#pragma unroll
    for (int r = 0; r < 4; ++r) inv[r] = 1.f / rowsum16(srow[r]);

    const int b = bh >> 4, h = bh & 15;
#pragma unroll
    for (int db = 0; db < 4; ++db)
#pragma unroll
        for (int r = 0; r < 4; ++r) {
            int si = q0 + 4 * g + r;
            attn[((size_t)(b * SEQ) + si) * HID + h * HD + db * 16 + c16] =
                f2bf(acc[db][r] * inv[r]);
        }
}

// ---------------- launch ----------------

extern "C" void kernel_launch(void* const* d_in, const int* in_sizes, int n_in,
                              void* d_out, int out_size, void* d_ws, size_t ws_size,
                              hipStream_t stream) {
    const float* x  = (const float*)d_in[0];
    const float* wq = (const float*)d_in[1];
    const float* bq = (const float*)d_in[2];
    const float* wk = (const float*)d_in[3];
    const float* bk = (const float*)d_in[4];
    const float* wv = (const float*)d_in[5];
    const float* bv = (const float*)d_in[6];
    const float* wo = (const float*)d_in[7];
    const float* bo = (const float*)d_in[8];
    float* out = (float*)d_out;

    char* ws = (char*)d_ws;
    // layout (bytes): xb 8MB | wqt,wkt,wvt,wot 2MB each | qb 8MB | kb 8MB | vt 8MB | attn 8MB
    unsigned short* xb   = (unsigned short*)(ws);
    unsigned short* wqt  = (unsigned short*)(ws + (8u << 20));
    unsigned short* wkt  = wqt + 1024 * 1024;
    unsigned short* wvt  = wkt + 1024 * 1024;
    unsigned short* wot  = wvt + 1024 * 1024;
    unsigned short* qb   = wot + 1024 * 1024;
    unsigned short* kbuf = qb + 4u * 1024 * 1024;
    unsigned short* vt   = kbuf + 4u * 1024 * 1024;
    unsigned short* attn = vt + 4u * 1024 * 1024;

    k_convert_x<<<dim3(2048), dim3(256), 0, stream>>>(x, xb);
    k_transpose_w<<<dim3(32, 32, 4), dim3(32, 8), 0, stream>>>(wq, wk, wv, wo,
                                                               wqt, wkt, wvt, wot);
    k_gemm_qkv<<<dim3(8, 32, 3), dim3(256), 0, stream>>>(xb, wqt, wkt, wvt,
                                                         bq, bk, bv, qb, kbuf, vt);
    k_attn<<<dim3(SEQ / 64, BATCH * NH), dim3(256), 0, stream>>>(qb, kbuf, vt, attn);
    k_gemm_out<<<dim3(8, 32), dim3(256), 0, stream>>>(attn, wot, bo, out);
}

// Round 5
// 189.366 us; speedup vs baseline: 1.0179x; 1.0143x over previous
//
#include <hip/hip_runtime.h>
#include <hip/hip_bf16.h>
#include <stdint.h>

#define BATCH 2
#define SEQ   2048
#define HID   1024
#define NH    16
#define HD    64
#define W2    128   // WINDOW/2

using bhalf8 = __attribute__((ext_vector_type(8))) short;
using fvec4  = __attribute__((ext_vector_type(4))) float;
using u16x8  = __attribute__((ext_vector_type(8))) unsigned short;

__device__ __forceinline__ unsigned short f2bf(float f) {
    union { float f; unsigned int u; } c; c.f = f;
    unsigned int u = c.u;
    u += 0x7FFFu + ((u >> 16) & 1u);   // RNE
    return (unsigned short)(u >> 16);
}

__device__ __forceinline__ fvec4 zero4() {
    fvec4 z = {0.f, 0.f, 0.f, 0.f};
    return z;
}

__device__ __forceinline__ void load_lds16(const void* g, void* l) {
    __builtin_amdgcn_global_load_lds(
        (const __attribute__((address_space(1))) void*)g,
        (__attribute__((address_space(3))) void*)l, 16, 0, 0);
}

__device__ __forceinline__ float rowmax16(float v) {
    v = fmaxf(v, __shfl_xor(v, 1));
    v = fmaxf(v, __shfl_xor(v, 2));
    v = fmaxf(v, __shfl_xor(v, 4));
    v = fmaxf(v, __shfl_xor(v, 8));
    return v;
}
__device__ __forceinline__ float rowsum16(float v) {
    v += __shfl_xor(v, 1);
    v += __shfl_xor(v, 2);
    v += __shfl_xor(v, 4);
    v += __shfl_xor(v, 8);
    return v;
}

// ---------------- conversion kernels ----------------

__global__ __launch_bounds__(256) void k_convert_x(const float* __restrict__ x,
                                                   unsigned short* __restrict__ xb) {
    int i = (blockIdx.x * 256 + threadIdx.x) * 8;
    float4 a = *(const float4*)(x + i);
    float4 b = *(const float4*)(x + i + 4);
    u16x8 o;
    o[0] = f2bf(a.x); o[1] = f2bf(a.y); o[2] = f2bf(a.z); o[3] = f2bf(a.w);
    o[4] = f2bf(b.x); o[5] = f2bf(b.y); o[6] = f2bf(b.z); o[7] = f2bf(b.w);
    *(u16x8*)(xb + i) = o;
}

// transpose [K][N] fp32 -> [N][K] bf16, 32x32 tiles
__global__ __launch_bounds__(256) void k_transpose_w(
    const float* __restrict__ w0, const float* __restrict__ w1,
    const float* __restrict__ w2, const float* __restrict__ w3,
    unsigned short* __restrict__ t0, unsigned short* __restrict__ t1,
    unsigned short* __restrict__ t2, unsigned short* __restrict__ t3) {
    int z = blockIdx.z;
    const float* src = (z == 0) ? w0 : (z == 1) ? w1 : (z == 2) ? w2 : w3;
    unsigned short* dst = (z == 0) ? t0 : (z == 1) ? t1 : (z == 2) ? t2 : t3;
    __shared__ float tile[32][33];
    int n0 = blockIdx.x * 32, k0 = blockIdx.y * 32;
    int tx = threadIdx.x, ty = threadIdx.y;
#pragma unroll
    for (int r = 0; r < 4; ++r)
        tile[ty + 8 * r][tx] = src[(size_t)(k0 + ty + 8 * r) * HID + n0 + tx];
    __syncthreads();
#pragma unroll
    for (int r = 0; r < 4; ++r)
        dst[(size_t)(n0 + ty + 8 * r) * HID + k0 + tx] = f2bf(tile[tx][ty + 8 * r]);
}

// ---------------- GEMM mainloop ----------------
// 128x128 tile, BK=32, 3-deep LDS pipeline, counted vmcnt(4), raw s_barrier.
// LDS tile layout: [row][4 granules of 8 bf16]; granule XOR-swizzled by
// (row>>1)&3 (bits 4-5 of byte addr; involution, row bits untouched).
// Staging pre-swizzles the GLOBAL source so LDS dest stays linear (rule #21).
// Read: lanes 0-15 hit 8 distinct bank-granules instead of 2 (8-way -> 2-way).

__device__ __forceinline__ void stage_tile(const unsigned short* __restrict__ A,
                                           const unsigned short* __restrict__ Bt,
                                           int m0, int n0, int k0,
                                           unsigned short* As, unsigned short* Bs,
                                           int t) {
#pragma unroll
    for (int i = 0; i < 2; ++i) {
        int slot = t + 256 * i;
        int row = slot >> 2, ch = slot & 3;
        int chs = ch ^ ((row >> 1) & 3);   // inverse-swizzle the source granule
        load_lds16(A + (size_t)(m0 + row) * HID + k0 + chs * 8, As + slot * 8);
        load_lds16(Bt + (size_t)(n0 + row) * HID + k0 + chs * 8, Bs + slot * 8);
    }
}

__device__ __forceinline__ void gemm_tile(const unsigned short* __restrict__ A,
                                          const unsigned short* __restrict__ Bt,
                                          int m0, int n0,
                                          unsigned short (*As)[128 * 32],
                                          unsigned short (*Bs)[128 * 32],
                                          fvec4 acc[4][4]) {
    const int t = threadIdx.x;
    const int lane = t & 63;
    const int wid = t >> 6;
    const int wr = wid >> 1, wc = wid & 1;
    const int c16 = lane & 15, g = lane >> 4;

#pragma unroll
    for (int mi = 0; mi < 4; ++mi)
#pragma unroll
        for (int ni = 0; ni < 4; ++ni) acc[mi][ni] = zero4();

    // prologue: 2 tiles in flight (8 loads/thread outstanding)
    stage_tile(A, Bt, m0, n0, 0, As[0], Bs[0], t);
    stage_tile(A, Bt, m0, n0, 32, As[1], Bs[1], t);

    int cur = 0, sb = 2;
    for (int k0 = 0; k0 < HID; k0 += 32) {
        // retire the 4 oldest loads (buf[cur]); keep next tile's 4 in flight
        if (k0 + 32 < HID)
            asm volatile("s_waitcnt vmcnt(4)" ::: "memory");
        else
            asm volatile("s_waitcnt vmcnt(0)" ::: "memory");
        asm volatile("s_waitcnt lgkmcnt(0)" ::: "memory");
        __builtin_amdgcn_sched_barrier(0);
        __builtin_amdgcn_s_barrier();

        // stage tile k0+64 into the buffer last read at k0-32 (safe: all waves
        // passed the barrier after consuming it)
        if (k0 + 64 < HID) {
            stage_tile(A, Bt, m0, n0, k0 + 64, As[sb], Bs[sb], t);
            sb = (sb == 2) ? 0 : sb + 1;
        }

        const unsigned short* Ab = As[cur];
        const unsigned short* Bb = Bs[cur];
        bhalf8 af[4], bf[4];
#pragma unroll
        for (int i = 0; i < 4; ++i) {
            int ra = wr * 64 + i * 16 + c16;
            int rb = wc * 64 + i * 16 + c16;
            af[i] = *(const bhalf8*)(Ab + ra * 32 + (g ^ ((ra >> 1) & 3)) * 8);
            bf[i] = *(const bhalf8*)(Bb + rb * 32 + (g ^ ((rb >> 1) & 3)) * 8);
        }
#pragma unroll
        for (int mi = 0; mi < 4; ++mi)
#pragma unroll
            for (int ni = 0; ni < 4; ++ni)
                acc[mi][ni] = __builtin_amdgcn_mfma_f32_16x16x32_bf16(
                    af[mi], bf[ni], acc[mi][ni], 0, 0, 0);
        cur = (cur == 2) ? 0 : cur + 1;
    }
}

// QKV projection: z=0 -> Q (scaled, [b,h,s,d]), z=1 -> K ([b,h,s,d]), z=2 -> V^T ([b,h,d,s])
__global__ __launch_bounds__(256) void k_gemm_qkv(
    const unsigned short* __restrict__ xb,
    const unsigned short* __restrict__ wqt, const unsigned short* __restrict__ wkt,
    const unsigned short* __restrict__ wvt,
    const float* __restrict__ bq, const float* __restrict__ bk, const float* __restrict__ bv,
    unsigned short* __restrict__ qb, unsigned short* __restrict__ kbuf,
    unsigned short* __restrict__ vt) {
    __shared__ unsigned short As[3][128 * 32];
    __shared__ unsigned short Bs[3][128 * 32];
    const int z = blockIdx.z;
    const unsigned short* Bt = (z == 0) ? wqt : (z == 1) ? wkt : wvt;
    const float* bias = (z == 0) ? bq : (z == 1) ? bk : bv;
    const int m0 = blockIdx.y * 128, n0 = blockIdx.x * 128;
    fvec4 acc[4][4];
    gemm_tile(xb, Bt, m0, n0, As, Bs, acc);

    const int lane = threadIdx.x & 63, wid = threadIdx.x >> 6;
    const int wr = wid >> 1, wc = wid & 1, c16 = lane & 15, g = lane >> 4;
#pragma unroll
    for (int mi = 0; mi < 4; ++mi) {
#pragma unroll
        for (int ni = 0; ni < 4; ++ni) {
            int gcol = n0 + wc * 64 + ni * 16 + c16;
            int h = gcol >> 6, d = gcol & 63;
            float bsv = bias[gcol];
#pragma unroll
            for (int r = 0; r < 4; ++r) {
                int grow = m0 + wr * 64 + mi * 16 + 4 * g + r;
                int b = grow >> 11, s = grow & (SEQ - 1);
                float v = acc[mi][ni][r] + bsv;
                if (z == 0)
                    qb[((size_t)(b * NH + h) * SEQ + s) * HD + d] = f2bf(v * 0.125f);
                else if (z == 1)
                    kbuf[((size_t)(b * NH + h) * SEQ + s) * HD + d] = f2bf(v);
                else
                    vt[((size_t)(b * NH + h) * HD + d) * SEQ + s] = f2bf(v);
            }
        }
    }
}

// Output projection -> fp32 out
__global__ __launch_bounds__(256) void k_gemm_out(
    const unsigned short* __restrict__ attn, const unsigned short* __restrict__ wot,
    const float* __restrict__ bo, float* __restrict__ out) {
    __shared__ unsigned short As[3][128 * 32];
    __shared__ unsigned short Bs[3][128 * 32];
    const int m0 = blockIdx.y * 128, n0 = blockIdx.x * 128;
    fvec4 acc[4][4];
    gemm_tile(attn, wot, m0, n0, As, Bs, acc);

    const int lane = threadIdx.x & 63, wid = threadIdx.x >> 6;
    const int wr = wid >> 1, wc = wid & 1, c16 = lane & 15, g = lane >> 4;
#pragma unroll
    for (int mi = 0; mi < 4; ++mi) {
#pragma unroll
        for (int ni = 0; ni < 4; ++ni) {
            int gcol = n0 + wc * 64 + ni * 16 + c16;
            float bsv = bo[gcol];
#pragma unroll
            for (int r = 0; r < 4; ++r) {
                int grow = m0 + wr * 64 + mi * 16 + 4 * g + r;
                out[(size_t)grow * HID + gcol] = acc[mi][ni][r] + bsv;
            }
        }
    }
}

// ---------------- windowed flash attention ----------------
// grid: (SEQ/64, BATCH*NH), block 256. Each wave: 16 query rows.
__global__ __launch_bounds__(256) void k_attn(
    const unsigned short* __restrict__ qb, const unsigned short* __restrict__ kbuf,
    const unsigned short* __restrict__ vt, unsigned short* __restrict__ attn) {
    const int bh = blockIdx.y;
    const int wid = threadIdx.x >> 6, lane = threadIdx.x & 63;
    const int g = lane >> 4, c16 = lane & 15;
    const int q0 = blockIdx.x * 64 + wid * 16;

    const unsigned short* Qp = qb + (size_t)bh * SEQ * HD;
    const unsigned short* Kp = kbuf + (size_t)bh * SEQ * HD;
    const unsigned short* Vp = vt + (size_t)bh * HD * SEQ;

    __shared__ unsigned short Plds[4][16 * 32];
    unsigned short* myP = Plds[wid];

    bhalf8 qf0, qf1;
    {
        const unsigned short* p = Qp + (size_t)(q0 + c16) * HD + g * 8;
        qf0 = *(const bhalf8*)p;
        qf1 = *(const bhalf8*)(p + 32);
    }
    fvec4 acc[4];
#pragma unroll
    for (int i = 0; i < 4; ++i) acc[i] = zero4();
    float mrow[4] = {-1e30f, -1e30f, -1e30f, -1e30f};
    float srow[4] = {0.f, 0.f, 0.f, 0.f};

    int kstart = q0 - W2; if (kstart < 0) kstart = 0; kstart &= ~31;
    int kend = q0 + 15 + W2; if (kend > SEQ - 1) kend = SEQ - 1;

    for (int t0 = kstart; t0 <= kend; t0 += 32) {
        fvec4 sc0 = zero4(), sc1 = zero4();
        {
            const unsigned short* kp = Kp + (size_t)(t0 + c16) * HD + g * 8;
            bhalf8 ka = *(const bhalf8*)kp;
            bhalf8 kb2 = *(const bhalf8*)(kp + 32);
            sc0 = __builtin_amdgcn_mfma_f32_16x16x32_bf16(qf0, ka, sc0, 0, 0, 0);
            sc0 = __builtin_amdgcn_mfma_f32_16x16x32_bf16(qf1, kb2, sc0, 0, 0, 0);
        }
        {
            const unsigned short* kp = Kp + (size_t)(t0 + 16 + c16) * HD + g * 8;
            bhalf8 ka = *(const bhalf8*)kp;
            bhalf8 kb2 = *(const bhalf8*)(kp + 32);
            sc1 = __builtin_amdgcn_mfma_f32_16x16x32_bf16(qf0, ka, sc1, 0, 0, 0);
            sc1 = __builtin_amdgcn_mfma_f32_16x16x32_bf16(qf1, kb2, sc1, 0, 0, 0);
        }
        // band mask
#pragma unroll
        for (int r = 0; r < 4; ++r) {
            int ia = q0 + 4 * g + r;
            int j0 = t0 + c16, j1 = t0 + 16 + c16;
            if (j0 < ia - W2 || j0 > ia + W2) sc0[r] = -1e30f;
            if (j1 < ia - W2 || j1 > ia + W2) sc1[r] = -1e30f;
        }
        // online softmax update
#pragma unroll
        for (int r = 0; r < 4; ++r) {
            float pm = rowmax16(fmaxf(sc0[r], sc1[r]));
            float mn = fmaxf(mrow[r], pm);
            float f = __expf(mrow[r] - mn);
            mrow[r] = mn;
            float p0 = __expf(sc0[r] - mn);
            float p1 = __expf(sc1[r] - mn);
            srow[r] = srow[r] * f + (p0 + p1);   // per-lane partial; reduced at end
#pragma unroll
            for (int db = 0; db < 4; ++db) acc[db][r] *= f;
            myP[(4 * g + r) * 32 + c16] = f2bf(p0);
            myP[(4 * g + r) * 32 + 16 + c16] = f2bf(p1);
        }
        asm volatile("s_waitcnt lgkmcnt(0)" ::: "memory");
        __builtin_amdgcn_sched_barrier(0);
        bhalf8 pf = *(const bhalf8*)(myP + c16 * 32 + g * 8);
#pragma unroll
        for (int db = 0; db < 4; ++db) {
            const unsigned short* vp = Vp + (size_t)(db * 16 + c16) * SEQ + t0 + g * 8;
            bhalf8 vf = *(const bhalf8*)vp;
            acc[db] = __builtin_amdgcn_mfma_f32_16x16x32_bf16(pf, vf, acc[db], 0, 0, 0);
        }
    }

    float inv[4];
#pragma unroll
    for (int r = 0; r < 4; ++r) inv[r] = 1.f / rowsum16(srow[r]);

    const int b = bh >> 4, h = bh & 15;
#pragma unroll
    for (int db = 0; db < 4; ++db)
#pragma unroll
        for (int r = 0; r < 4; ++r) {
            int si = q0 + 4 * g + r;
            attn[((size_t)(b * SEQ) + si) * HID + h * HD + db * 16 + c16] =
                f2bf(acc[db][r] * inv[r]);
        }
}

// ---------------- launch ----------------

extern "C" void kernel_launch(void* const* d_in, const int* in_sizes, int n_in,
                              void* d_out, int out_size, void* d_ws, size_t ws_size,
                              hipStream_t stream) {
    const float* x  = (const float*)d_in[0];
    const float* wq = (const float*)d_in[1];
    const float* bq = (const float*)d_in[2];
    const float* wk = (const float*)d_in[3];
    const float* bk = (const float*)d_in[4];
    const float* wv = (const float*)d_in[5];
    const float* bv = (const float*)d_in[6];
    const float* wo = (const float*)d_in[7];
    const float* bo = (const float*)d_in[8];
    float* out = (float*)d_out;

    char* ws = (char*)d_ws;
    // layout (bytes): xb 8MB | wqt,wkt,wvt,wot 2MB each | qb 8MB | kb 8MB | vt 8MB | attn 8MB
    unsigned short* xb   = (unsigned short*)(ws);
    unsigned short* wqt  = (unsigned short*)(ws + (8u << 20));
    unsigned short* wkt  = wqt + 1024 * 1024;
    unsigned short* wvt  = wkt + 1024 * 1024;
    unsigned short* wot  = wvt + 1024 * 1024;
    unsigned short* qb   = wot + 1024 * 1024;
    unsigned short* kbuf = qb + 4u * 1024 * 1024;
    unsigned short* vt   = kbuf + 4u * 1024 * 1024;
    unsigned short* attn = vt + 4u * 1024 * 1024;

    k_convert_x<<<dim3(2048), dim3(256), 0, stream>>>(x, xb);
    k_transpose_w<<<dim3(32, 32, 4), dim3(32, 8), 0, stream>>>(wq, wk, wv, wo,
                                                               wqt, wkt, wvt, wot);
    k_gemm_qkv<<<dim3(8, 32, 3), dim3(256), 0, stream>>>(xb, wqt, wkt, wvt,
                                                         bq, bk, bv, qb, kbuf, vt);
    k_attn<<<dim3(SEQ / 64, BATCH * NH), dim3(256), 0, stream>>>(qb, kbuf, vt, attn);
    k_gemm_out<<<dim3(8, 32), dim3(256), 0, stream>>>(attn, wot, bo, out);
}

// Round 8
// 181.169 us; speedup vs baseline: 1.0639x; 1.0452x over previous
//
#include <hip/hip_runtime.h>
#include <hip/hip_bf16.h>
#include <stdint.h>

#define BATCH 2
#define SEQ   2048
#define HID   1024
#define NH    16
#define HD    64
#define W2    128   // WINDOW/2

using bhalf8 = __attribute__((ext_vector_type(8))) short;
using fvec4  = __attribute__((ext_vector_type(4))) float;
using u16x8  = __attribute__((ext_vector_type(8))) unsigned short;

__device__ __forceinline__ unsigned short f2bf(float f) {
    union { float f; unsigned int u; } c; c.f = f;
    unsigned int u = c.u;
    u += 0x7FFFu + ((u >> 16) & 1u);   // RNE
    return (unsigned short)(u >> 16);
}

__device__ __forceinline__ fvec4 zero4() {
    fvec4 z = {0.f, 0.f, 0.f, 0.f};
    return z;
}

__device__ __forceinline__ void load_lds16(const void* g, void* l) {
    __builtin_amdgcn_global_load_lds(
        (const __attribute__((address_space(1))) void*)g,
        (__attribute__((address_space(3))) void*)l, 16, 0, 0);
}

__device__ __forceinline__ float rowmax16(float v) {
    v = fmaxf(v, __shfl_xor(v, 1));
    v = fmaxf(v, __shfl_xor(v, 2));
    v = fmaxf(v, __shfl_xor(v, 4));
    v = fmaxf(v, __shfl_xor(v, 8));
    return v;
}
__device__ __forceinline__ float rowsum16(float v) {
    v += __shfl_xor(v, 1);
    v += __shfl_xor(v, 2);
    v += __shfl_xor(v, 4);
    v += __shfl_xor(v, 8);
    return v;
}

// ---------------- conversion kernels ----------------

__global__ __launch_bounds__(256) void k_convert_x(const float* __restrict__ x,
                                                   unsigned short* __restrict__ xb) {
    int i = (blockIdx.x * 256 + threadIdx.x) * 8;
    float4 a = *(const float4*)(x + i);
    float4 b = *(const float4*)(x + i + 4);
    u16x8 o;
    o[0] = f2bf(a.x); o[1] = f2bf(a.y); o[2] = f2bf(a.z); o[3] = f2bf(a.w);
    o[4] = f2bf(b.x); o[5] = f2bf(b.y); o[6] = f2bf(b.z); o[7] = f2bf(b.w);
    *(u16x8*)(xb + i) = o;
}

// transpose [K][N] fp32 -> [N][K] bf16, 32x32 tiles
__global__ __launch_bounds__(256) void k_transpose_w(
    const float* __restrict__ w0, const float* __restrict__ w1,
    const float* __restrict__ w2, const float* __restrict__ w3,
    unsigned short* __restrict__ t0, unsigned short* __restrict__ t1,
    unsigned short* __restrict__ t2, unsigned short* __restrict__ t3) {
    int z = blockIdx.z;
    const float* src = (z == 0) ? w0 : (z == 1) ? w1 : (z == 2) ? w2 : w3;
    unsigned short* dst = (z == 0) ? t0 : (z == 1) ? t1 : (z == 2) ? t2 : t3;
    __shared__ float tile[32][33];
    int n0 = blockIdx.x * 32, k0 = blockIdx.y * 32;
    int tx = threadIdx.x, ty = threadIdx.y;
#pragma unroll
    for (int r = 0; r < 4; ++r)
        tile[ty + 8 * r][tx] = src[(size_t)(k0 + ty + 8 * r) * HID + n0 + tx];
    __syncthreads();
#pragma unroll
    for (int r = 0; r < 4; ++r)
        dst[(size_t)(n0 + ty + 8 * r) * HID + k0 + tx] = f2bf(tile[tx][ty + 8 * r]);
}

// ---------------- GEMM mainloop ----------------
// 128x128 tile, BK=32, 8 waves (512 threads, wave grid 2M x 4N, acc[4][2]),
// 3-deep LDS pipeline, counted vmcnt(2), raw s_barrier, XOR-swizzled LDS
// (granule bits ^= (row>>1)&3; source pre-swizzled so LDS dest stays linear).
// Measured: bank conflicts == 0 with this swizzle (R5).

__device__ __forceinline__ void stage_tile(const unsigned short* __restrict__ A,
                                           const unsigned short* __restrict__ Bt,
                                           int m0, int n0, int k0,
                                           unsigned short* As, unsigned short* Bs,
                                           int t) {
    int row = t >> 2, ch = t & 3;
    int chs = ch ^ ((row >> 1) & 3);   // inverse-swizzle the source granule
    load_lds16(A + (size_t)(m0 + row) * HID + k0 + chs * 8, As + t * 8);
    load_lds16(Bt + (size_t)(n0 + row) * HID + k0 + chs * 8, Bs + t * 8);
}

__device__ __forceinline__ void gemm_tile8(const unsigned short* __restrict__ A,
                                           const unsigned short* __restrict__ Bt,
                                           int m0, int n0,
                                           unsigned short* As, unsigned short* Bs,
                                           fvec4 acc[4][2]) {
    const int t = threadIdx.x;
    const int lane = t & 63;
    const int wid = t >> 6;
    const int wr = wid >> 2, wc = wid & 3;
    const int c16 = lane & 15, g = lane >> 4;

#pragma unroll
    for (int mi = 0; mi < 4; ++mi)
#pragma unroll
        for (int ni = 0; ni < 2; ++ni) acc[mi][ni] = zero4();

    // prologue: 2 tiles in flight (4 loads/thread outstanding)
    stage_tile(A, Bt, m0, n0, 0, As, Bs, t);
    stage_tile(A, Bt, m0, n0, 32, As + 4096, Bs + 4096, t);

    int cur = 0, sb = 2;
    for (int k0 = 0; k0 < HID; k0 += 32) {
        // retire the 2 oldest loads (tile cur); keep next tile's 2 in flight
        if (k0 + 32 < HID)
            asm volatile("s_waitcnt vmcnt(2)" ::: "memory");
        else
            asm volatile("s_waitcnt vmcnt(0)" ::: "memory");
        asm volatile("s_waitcnt lgkmcnt(0)" ::: "memory");
        __builtin_amdgcn_sched_barrier(0);
        __builtin_amdgcn_s_barrier();

        if (k0 + 64 < HID) {
            stage_tile(A, Bt, m0, n0, k0 + 64, As + sb * 4096, Bs + sb * 4096, t);
            sb = (sb == 2) ? 0 : sb + 1;
        }

        const unsigned short* Ab = As + cur * 4096;
        const unsigned short* Bb = Bs + cur * 4096;
        bhalf8 af[4], bf[2];
#pragma unroll
        for (int i = 0; i < 4; ++i) {
            int ra = wr * 64 + i * 16 + c16;
            af[i] = *(const bhalf8*)(Ab + ra * 32 + (g ^ ((ra >> 1) & 3)) * 8);
        }
#pragma unroll
        for (int i = 0; i < 2; ++i) {
            int rb = wc * 32 + i * 16 + c16;
            bf[i] = *(const bhalf8*)(Bb + rb * 32 + (g ^ ((rb >> 1) & 3)) * 8);
        }
#pragma unroll
        for (int mi = 0; mi < 4; ++mi)
#pragma unroll
            for (int ni = 0; ni < 2; ++ni)
                acc[mi][ni] = __builtin_amdgcn_mfma_f32_16x16x32_bf16(
                    af[mi], bf[ni], acc[mi][ni], 0, 0, 0);
        cur = (cur == 2) ? 0 : cur + 1;
    }
}

// QKV projection: z=0 -> Q (scaled, [b,h,s,d]), z=1 -> K ([b,h,s,d]), z=2 -> V^T ([b,h,d,s])
__global__ __launch_bounds__(512, 6) void k_gemm_qkv(
    const unsigned short* __restrict__ xb,
    const unsigned short* __restrict__ wqt, const unsigned short* __restrict__ wkt,
    const unsigned short* __restrict__ wvt,
    const float* __restrict__ bq, const float* __restrict__ bk, const float* __restrict__ bv,
    unsigned short* __restrict__ qb, unsigned short* __restrict__ kbuf,
    unsigned short* __restrict__ vt) {
    __shared__ unsigned short SH[2][3 * 128 * 32];   // As triple | Bs triple (48 KB)
    const int z = blockIdx.z;
    const unsigned short* Bt = (z == 0) ? wqt : (z == 1) ? wkt : wvt;
    const float* bias = (z == 0) ? bq : (z == 1) ? bk : bv;
    const int m0 = blockIdx.y * 128, n0 = blockIdx.x * 128;
    fvec4 acc[4][2];
    gemm_tile8(xb, Bt, m0, n0, SH[0], SH[1], acc);

    const int t = threadIdx.x, lane = t & 63, wid = t >> 6;
    const int wr = wid >> 2, wc = wid & 3, c16 = lane & 15, g = lane >> 4;

    if (z != 2) {
#pragma unroll
        for (int mi = 0; mi < 4; ++mi) {
#pragma unroll
            for (int ni = 0; ni < 2; ++ni) {
                int gcol = n0 + wc * 32 + ni * 16 + c16;
                int h = gcol >> 6, d = gcol & 63;
                float bsv = bias[gcol];
#pragma unroll
                for (int r = 0; r < 4; ++r) {
                    int grow = m0 + wr * 64 + mi * 16 + 4 * g + r;
                    int b = grow >> 11, s = grow & (SEQ - 1);
                    float v = acc[mi][ni][r] + bsv;
                    if (z == 0)
                        qb[((size_t)(b * NH + h) * SEQ + s) * HD + d] = f2bf(v * 0.125f);
                    else
                        kbuf[((size_t)(b * NH + h) * SEQ + s) * HD + d] = f2bf(v);
                }
            }
        }
    } else {
        // V^T: transpose through LDS, store coalesced along s.
        unsigned short* VL = &SH[0][0];   // 128 x 132 (padded), 33.8 KB
        __syncthreads();                  // everyone done reading staging buffers
#pragma unroll
        for (int mi = 0; mi < 4; ++mi)
#pragma unroll
            for (int ni = 0; ni < 2; ++ni) {
                int dl = wc * 32 + ni * 16 + c16;
                float bsv = bias[n0 + dl];
#pragma unroll
                for (int r = 0; r < 4; ++r) {
                    int sl = wr * 64 + mi * 16 + 4 * g + r;
                    VL[dl * 132 + sl] = f2bf(acc[mi][ni][r] + bsv);
                }
            }
        __syncthreads();
        const int b = m0 >> 11, sbase = m0 & (SEQ - 1);
#pragma unroll
        for (int it = 0; it < 4; ++it) {
            int slot = t + 512 * it;
            int dl = slot >> 4, ch = slot & 15;
            int gcol = n0 + dl;
            int h = gcol >> 6, d = gcol & 63;
            u16x8 v = *(const u16x8*)(VL + dl * 132 + ch * 8);
            *(u16x8*)(vt + ((size_t)(b * NH + h) * HD + d) * SEQ + sbase + ch * 8) = v;
        }
    }
}

// Output projection -> fp32 out
__global__ __launch_bounds__(512, 6) void k_gemm_out(
    const unsigned short* __restrict__ attn, const unsigned short* __restrict__ wot,
    const float* __restrict__ bo, float* __restrict__ out) {
    __shared__ unsigned short SH[2][3 * 128 * 32];
    const int m0 = blockIdx.y * 128, n0 = blockIdx.x * 128;
    fvec4 acc[4][2];
    gemm_tile8(attn, wot, m0, n0, SH[0], SH[1], acc);

    const int lane = threadIdx.x & 63, wid = threadIdx.x >> 6;
    const int wr = wid >> 2, wc = wid & 3, c16 = lane & 15, g = lane >> 4;
#pragma unroll
    for (int mi = 0; mi < 4; ++mi) {
#pragma unroll
        for (int ni = 0; ni < 2; ++ni) {
            int gcol = n0 + wc * 32 + ni * 16 + c16;
            float bsv = bo[gcol];
#pragma unroll
            for (int r = 0; r < 4; ++r) {
                int grow = m0 + wr * 64 + mi * 16 + 4 * g + r;
                out[(size_t)grow * HID + gcol] = acc[mi][ni][r] + bsv;
            }
        }
    }
}

// ---------------- windowed flash attention ----------------
// grid: (SEQ/64, BATCH*NH), block 256. Each wave: 16 query rows.
__global__ __launch_bounds__(256) void k_attn(
    const unsigned short* __restrict__ qb, const unsigned short* __restrict__ kbuf,
    const unsigned short* __restrict__ vt, unsigned short* __restrict__ attn) {
    const int bh = blockIdx.y;
    const int wid = threadIdx.x >> 6, lane = threadIdx.x & 63;
    const int g = lane >> 4, c16 = lane & 15;
    const int q0 = blockIdx.x * 64 + wid * 16;

    const unsigned short* Qp = qb + (size_t)bh * SEQ * HD;
    const unsigned short* Kp = kbuf + (size_t)bh * SEQ * HD;
    const unsigned short* Vp = vt + (size_t)bh * HD * SEQ;

    __shared__ unsigned short Plds[4][16 * 32];
    unsigned short* myP = Plds[wid];

    bhalf8 qf0, qf1;
    {
        const unsigned short* p = Qp + (size_t)(q0 + c16) * HD + g * 8;
        qf0 = *(const bhalf8*)p;
        qf1 = *(const bhalf8*)(p + 32);
    }
    fvec4 acc[4];
#pragma unroll
    for (int i = 0; i < 4; ++i) acc[i] = zero4();
    float mrow[4] = {-1e30f, -1e30f, -1e30f, -1e30f};
    float srow[4] = {0.f, 0.f, 0.f, 0.f};

    int kstart = q0 - W2; if (kstart < 0) kstart = 0; kstart &= ~31;
    int kend = q0 + 15 + W2; if (kend > SEQ - 1) kend = SEQ - 1;

    for (int t0 = kstart; t0 <= kend; t0 += 32) {
        fvec4 sc0 = zero4(), sc1 = zero4();
        {
            const unsigned short* kp = Kp + (size_t)(t0 + c16) * HD + g * 8;
            bhalf8 ka = *(const bhalf8*)kp;
            bhalf8 kb2 = *(const bhalf8*)(kp + 32);
            sc0 = __builtin_amdgcn_mfma_f32_16x16x32_bf16(qf0, ka, sc0, 0, 0, 0);
            sc0 = __builtin_amdgcn_mfma_f32_16x16x32_bf16(qf1, kb2, sc0, 0, 0, 0);
        }
        {
            const unsigned short* kp = Kp + (size_t)(t0 + 16 + c16) * HD + g * 8;
            bhalf8 ka = *(const bhalf8*)kp;
            bhalf8 kb2 = *(const bhalf8*)(kp + 32);
            sc1 = __builtin_amdgcn_mfma_f32_16x16x32_bf16(qf0, ka, sc1, 0, 0, 0);
            sc1 = __builtin_amdgcn_mfma_f32_16x16x32_bf16(qf1, kb2, sc1, 0, 0, 0);
        }
        // band mask
#pragma unroll
        for (int r = 0; r < 4; ++r) {
            int ia = q0 + 4 * g + r;
            int j0 = t0 + c16, j1 = t0 + 16 + c16;
            if (j0 < ia - W2 || j0 > ia + W2) sc0[r] = -1e30f;
            if (j1 < ia - W2 || j1 > ia + W2) sc1[r] = -1e30f;
        }
        // online softmax update
#pragma unroll
        for (int r = 0; r < 4; ++r) {
            float pm = rowmax16(fmaxf(sc0[r], sc1[r]));
            float mn = fmaxf(mrow[r], pm);
            float f = __expf(mrow[r] - mn);
            mrow[r] = mn;
            float p0 = __expf(sc0[r] - mn);
            float p1 = __expf(sc1[r] - mn);
            srow[r] = srow[r] * f + (p0 + p1);   // per-lane partial; reduced at end
#pragma unroll
            for (int db = 0; db < 4; ++db) acc[db][r] *= f;
            myP[(4 * g + r) * 32 + c16] = f2bf(p0);
            myP[(4 * g + r) * 32 + 16 + c16] = f2bf(p1);
        }
        asm volatile("s_waitcnt lgkmcnt(0)" ::: "memory");
        __builtin_amdgcn_sched_barrier(0);
        bhalf8 pf = *(const bhalf8*)(myP + c16 * 32 + g * 8);
#pragma unroll
        for (int db = 0; db < 4; ++db) {
            const unsigned short* vp = Vp + (size_t)(db * 16 + c16) * SEQ + t0 + g * 8;
            bhalf8 vf = *(const bhalf8*)vp;
            acc[db] = __builtin_amdgcn_mfma_f32_16x16x32_bf16(pf, vf, acc[db], 0, 0, 0);
        }
    }

    float inv[4];
#pragma unroll
    for (int r = 0; r < 4; ++r) inv[r] = 1.f / rowsum16(srow[r]);

    const int b = bh >> 4, h = bh & 15;
#pragma unroll
    for (int db = 0; db < 4; ++db)
#pragma unroll
        for (int r = 0; r < 4; ++r) {
            int si = q0 + 4 * g + r;
            attn[((size_t)(b * SEQ) + si) * HID + h * HD + db * 16 + c16] =
                f2bf(acc[db][r] * inv[r]);
        }
}

// ---------------- launch ----------------

extern "C" void kernel_launch(void* const* d_in, const int* in_sizes, int n_in,
                              void* d_out, int out_size, void* d_ws, size_t ws_size,
                              hipStream_t stream) {
    const float* x  = (const float*)d_in[0];
    const float* wq = (const float*)d_in[1];
    const float* bq = (const float*)d_in[2];
    const float* wk = (const float*)d_in[3];
    const float* bk = (const float*)d_in[4];
    const float* wv = (const float*)d_in[5];
    const float* bv = (const float*)d_in[6];
    const float* wo = (const float*)d_in[7];
    const float* bo = (const float*)d_in[8];
    float* out = (float*)d_out;

    char* ws = (char*)d_ws;
    // layout (bytes): xb 8MB | wqt,wkt,wvt,wot 2MB each | qb 8MB | kb 8MB | vt 8MB | attn 8MB
    unsigned short* xb   = (unsigned short*)(ws);
    unsigned short* wqt  = (unsigned short*)(ws + (8u << 20));
    unsigned short* wkt  = wqt + 1024 * 1024;
    unsigned short* wvt  = wkt + 1024 * 1024;
    unsigned short* wot  = wvt + 1024 * 1024;
    unsigned short* qb   = wot + 1024 * 1024;
    unsigned short* kbuf = qb + 4u * 1024 * 1024;
    unsigned short* vt   = kbuf + 4u * 1024 * 1024;
    unsigned short* attn = vt + 4u * 1024 * 1024;

    k_convert_x<<<dim3(2048), dim3(256), 0, stream>>>(x, xb);
    k_transpose_w<<<dim3(32, 32, 4), dim3(32, 8), 0, stream>>>(wq, wk, wv, wo,
                                                               wqt, wkt, wvt, wot);
    k_gemm_qkv<<<dim3(8, 32, 3), dim3(512), 0, stream>>>(xb, wqt, wkt, wvt,
                                                         bq, bk, bv, qb, kbuf, vt);
    k_attn<<<dim3(SEQ / 64, BATCH * NH), dim3(256), 0, stream>>>(qb, kbuf, vt, attn);
    k_gemm_out<<<dim3(8, 32), dim3(512), 0, stream>>>(attn, wot, bo, out);
}

// Round 9
// 180.447 us; speedup vs baseline: 1.0682x; 1.0040x over previous
//
#include <hip/hip_runtime.h>
#include <hip/hip_bf16.h>
#include <stdint.h>

#define BATCH 2
#define SEQ   2048
#define HID   1024
#define NH    16
#define HD    64
#define W2    128   // WINDOW/2

using bhalf8 = __attribute__((ext_vector_type(8))) short;
using fvec4  = __attribute__((ext_vector_type(4))) float;
using u16x8  = __attribute__((ext_vector_type(8))) unsigned short;

__device__ __forceinline__ unsigned short f2bf(float f) {
    union { float f; unsigned int u; } c; c.f = f;
    unsigned int u = c.u;
    u += 0x7FFFu + ((u >> 16) & 1u);   // RNE
    return (unsigned short)(u >> 16);
}

__device__ __forceinline__ fvec4 zero4() {
    fvec4 z = {0.f, 0.f, 0.f, 0.f};
    return z;
}

__device__ __forceinline__ void load_lds16(const void* g, void* l) {
    __builtin_amdgcn_global_load_lds(
        (const __attribute__((address_space(1))) void*)g,
        (__attribute__((address_space(3))) void*)l, 16, 0, 0);
}

__device__ __forceinline__ float rowmax16(float v) {
    v = fmaxf(v, __shfl_xor(v, 1));
    v = fmaxf(v, __shfl_xor(v, 2));
    v = fmaxf(v, __shfl_xor(v, 4));
    v = fmaxf(v, __shfl_xor(v, 8));
    return v;
}
__device__ __forceinline__ float rowsum16(float v) {
    v += __shfl_xor(v, 1);
    v += __shfl_xor(v, 2);
    v += __shfl_xor(v, 4);
    v += __shfl_xor(v, 8);
    return v;
}

// ---------------- conversion kernels ----------------

__global__ __launch_bounds__(256) void k_convert_x(const float* __restrict__ x,
                                                   unsigned short* __restrict__ xb) {
    int i = (blockIdx.x * 256 + threadIdx.x) * 8;
    float4 a = *(const float4*)(x + i);
    float4 b = *(const float4*)(x + i + 4);
    u16x8 o;
    o[0] = f2bf(a.x); o[1] = f2bf(a.y); o[2] = f2bf(a.z); o[3] = f2bf(a.w);
    o[4] = f2bf(b.x); o[5] = f2bf(b.y); o[6] = f2bf(b.z); o[7] = f2bf(b.w);
    *(u16x8*)(xb + i) = o;
}

// transpose [K][N] fp32 -> [N][K] bf16, 32x32 tiles
__global__ __launch_bounds__(256) void k_transpose_w(
    const float* __restrict__ w0, const float* __restrict__ w1,
    const float* __restrict__ w2, const float* __restrict__ w3,
    unsigned short* __restrict__ t0, unsigned short* __restrict__ t1,
    unsigned short* __restrict__ t2, unsigned short* __restrict__ t3) {
    int z = blockIdx.z;
    const float* src = (z == 0) ? w0 : (z == 1) ? w1 : (z == 2) ? w2 : w3;
    unsigned short* dst = (z == 0) ? t0 : (z == 1) ? t1 : (z == 2) ? t2 : t3;
    __shared__ float tile[32][33];
    int n0 = blockIdx.x * 32, k0 = blockIdx.y * 32;
    int tx = threadIdx.x, ty = threadIdx.y;
#pragma unroll
    for (int r = 0; r < 4; ++r)
        tile[ty + 8 * r][tx] = src[(size_t)(k0 + ty + 8 * r) * HID + n0 + tx];
    __syncthreads();
#pragma unroll
    for (int r = 0; r < 4; ++r)
        dst[(size_t)(n0 + ty + 8 * r) * HID + k0 + tx] = f2bf(tile[tx][ty + 8 * r]);
}

// ---------------- GEMM mainloop ----------------
// 128x128 tile, BK=64, 8 waves (512 threads, wave grid 2M x 4N, acc[4][2]),
// 2-deep LDS double-buffer (64 KB -> 2 blocks/CU, 16 waves/CU), T3-min
// ordering: [vmcnt(0) wait cur] [barrier] [stage next] [ds_read+MFMA cur].
// Stage latency hides under the full 16-MFMA compute phase; 16 barriers
// per block instead of 32. LDS granule XOR-swizzle: granule ^= row&7
// (rows are 128 B apart; 16-lane column read spreads over 8 granule slots
// = 2-way aliasing = free). Source pre-swizzled so LDS dest stays linear.
// T5 setprio around the MFMA cluster.

__device__ __forceinline__ void stage_tile64(const unsigned short* __restrict__ A,
                                             const unsigned short* __restrict__ Bt,
                                             int m0, int n0, int k0,
                                             unsigned short* As, unsigned short* Bs,
                                             int t) {
#pragma unroll
    for (int i = 0; i < 2; ++i) {
        int chunk = t + 512 * i;           // 1024 chunks of 16 B per matrix
        int row = chunk >> 3, ch = chunk & 7;
        int chs = ch ^ (row & 7);          // inverse-swizzle the source granule
        load_lds16(A + (size_t)(m0 + row) * HID + k0 + chs * 8, As + chunk * 8);
        load_lds16(Bt + (size_t)(n0 + row) * HID + k0 + chs * 8, Bs + chunk * 8);
    }
}

__device__ __forceinline__ void gemm_tile8(const unsigned short* __restrict__ A,
                                           const unsigned short* __restrict__ Bt,
                                           int m0, int n0,
                                           unsigned short* As, unsigned short* Bs,
                                           fvec4 acc[4][2]) {
    const int t = threadIdx.x;
    const int lane = t & 63;
    const int wid = t >> 6;
    const int wr = wid >> 2, wc = wid & 3;
    const int c16 = lane & 15, g = lane >> 4;

#pragma unroll
    for (int mi = 0; mi < 4; ++mi)
#pragma unroll
        for (int ni = 0; ni < 2; ++ni) acc[mi][ni] = zero4();

    stage_tile64(A, Bt, m0, n0, 0, As, Bs, t);

    int cur = 0;
    for (int k0 = 0; k0 < HID; k0 += 64) {
        // my loads for tile cur done; barrier => ALL waves' loads done and
        // all waves finished reading buf[cur^1] last step => safe to restage it
        asm volatile("s_waitcnt vmcnt(0)" ::: "memory");
        __builtin_amdgcn_sched_barrier(0);
        __builtin_amdgcn_s_barrier();

        if (k0 + 64 < HID)
            stage_tile64(A, Bt, m0, n0, k0 + 64,
                         As + (cur ^ 1) * 8192, Bs + (cur ^ 1) * 8192, t);

        const unsigned short* Ab = As + cur * 8192;
        const unsigned short* Bb = Bs + cur * 8192;
        bhalf8 af[2][4], bf[2][2];
#pragma unroll
        for (int ks = 0; ks < 2; ++ks) {
#pragma unroll
            for (int i = 0; i < 4; ++i) {
                int ra = wr * 64 + i * 16 + c16;
                af[ks][i] = *(const bhalf8*)(Ab + ra * 64 + ((4 * ks + g) ^ (ra & 7)) * 8);
            }
#pragma unroll
            for (int i = 0; i < 2; ++i) {
                int rb = wc * 32 + i * 16 + c16;
                bf[ks][i] = *(const bhalf8*)(Bb + rb * 64 + ((4 * ks + g) ^ (rb & 7)) * 8);
            }
        }
        __builtin_amdgcn_s_setprio(1);
#pragma unroll
        for (int ks = 0; ks < 2; ++ks)
#pragma unroll
            for (int mi = 0; mi < 4; ++mi)
#pragma unroll
                for (int ni = 0; ni < 2; ++ni)
                    acc[mi][ni] = __builtin_amdgcn_mfma_f32_16x16x32_bf16(
                        af[ks][mi], bf[ks][ni], acc[mi][ni], 0, 0, 0);
        __builtin_amdgcn_s_setprio(0);
        cur ^= 1;
    }
}

// QKV projection: z=0 -> Q (scaled, [b,h,s,d]), z=1 -> K ([b,h,s,d]), z=2 -> V^T ([b,h,d,s])
__global__ __launch_bounds__(512, 4) void k_gemm_qkv(
    const unsigned short* __restrict__ xb,
    const unsigned short* __restrict__ wqt, const unsigned short* __restrict__ wkt,
    const unsigned short* __restrict__ wvt,
    const float* __restrict__ bq, const float* __restrict__ bk, const float* __restrict__ bv,
    unsigned short* __restrict__ qb, unsigned short* __restrict__ kbuf,
    unsigned short* __restrict__ vt) {
    __shared__ unsigned short SH[2][2 * 128 * 64];   // As dbuf | Bs dbuf (64 KB)
    const int z = blockIdx.z;
    const unsigned short* Bt = (z == 0) ? wqt : (z == 1) ? wkt : wvt;
    const float* bias = (z == 0) ? bq : (z == 1) ? bk : bv;
    const int m0 = blockIdx.y * 128, n0 = blockIdx.x * 128;
    fvec4 acc[4][2];
    gemm_tile8(xb, Bt, m0, n0, SH[0], SH[1], acc);

    const int t = threadIdx.x, lane = t & 63, wid = t >> 6;
    const int wr = wid >> 2, wc = wid & 3, c16 = lane & 15, g = lane >> 4;

    if (z != 2) {
#pragma unroll
        for (int mi = 0; mi < 4; ++mi) {
#pragma unroll
            for (int ni = 0; ni < 2; ++ni) {
                int gcol = n0 + wc * 32 + ni * 16 + c16;
                int h = gcol >> 6, d = gcol & 63;
                float bsv = bias[gcol];
#pragma unroll
                for (int r = 0; r < 4; ++r) {
                    int grow = m0 + wr * 64 + mi * 16 + 4 * g + r;
                    int b = grow >> 11, s = grow & (SEQ - 1);
                    float v = acc[mi][ni][r] + bsv;
                    if (z == 0)
                        qb[((size_t)(b * NH + h) * SEQ + s) * HD + d] = f2bf(v * 0.125f);
                    else
                        kbuf[((size_t)(b * NH + h) * SEQ + s) * HD + d] = f2bf(v);
                }
            }
        }
    } else {
        // V^T: transpose through LDS, store coalesced along s.
        unsigned short* VL = &SH[0][0];   // 128 x 132 (padded), 33 KB
        __syncthreads();                  // everyone done reading staging buffers
#pragma unroll
        for (int mi = 0; mi < 4; ++mi)
#pragma unroll
            for (int ni = 0; ni < 2; ++ni) {
                int dl = wc * 32 + ni * 16 + c16;
                float bsv = bias[n0 + dl];
#pragma unroll
                for (int r = 0; r < 4; ++r) {
                    int sl = wr * 64 + mi * 16 + 4 * g + r;
                    VL[dl * 132 + sl] = f2bf(acc[mi][ni][r] + bsv);
                }
            }
        __syncthreads();
        const int b = m0 >> 11, sbase = m0 & (SEQ - 1);
#pragma unroll
        for (int it = 0; it < 4; ++it) {
            int slot = t + 512 * it;
            int dl = slot >> 4, ch = slot & 15;
            int gcol = n0 + dl;
            int h = gcol >> 6, d = gcol & 63;
            u16x8 v = *(const u16x8*)(VL + dl * 132 + ch * 8);
            *(u16x8*)(vt + ((size_t)(b * NH + h) * HD + d) * SEQ + sbase + ch * 8) = v;
        }
    }
}

// Output projection -> fp32 out
__global__ __launch_bounds__(512, 4) void k_gemm_out(
    const unsigned short* __restrict__ attn, const unsigned short* __restrict__ wot,
    const float* __restrict__ bo, float* __restrict__ out) {
    __shared__ unsigned short SH[2][2 * 128 * 64];
    const int m0 = blockIdx.y * 128, n0 = blockIdx.x * 128;
    fvec4 acc[4][2];
    gemm_tile8(attn, wot, m0, n0, SH[0], SH[1], acc);

    const int lane = threadIdx.x & 63, wid = threadIdx.x >> 6;
    const int wr = wid >> 2, wc = wid & 3, c16 = lane & 15, g = lane >> 4;
#pragma unroll
    for (int mi = 0; mi < 4; ++mi) {
#pragma unroll
        for (int ni = 0; ni < 2; ++ni) {
            int gcol = n0 + wc * 32 + ni * 16 + c16;
            float bsv = bo[gcol];
#pragma unroll
            for (int r = 0; r < 4; ++r) {
                int grow = m0 + wr * 64 + mi * 16 + 4 * g + r;
                out[(size_t)grow * HID + gcol] = acc[mi][ni][r] + bsv;
            }
        }
    }
}

// ---------------- windowed flash attention ----------------
// grid: (SEQ/64, BATCH*NH), block 256. Each wave: 16 query rows.
__global__ __launch_bounds__(256) void k_attn(
    const unsigned short* __restrict__ qb, const unsigned short* __restrict__ kbuf,
    const unsigned short* __restrict__ vt, unsigned short* __restrict__ attn) {
    const int bh = blockIdx.y;
    const int wid = threadIdx.x >> 6, lane = threadIdx.x & 63;
    const int g = lane >> 4, c16 = lane & 15;
    const int q0 = blockIdx.x * 64 + wid * 16;

    const unsigned short* Qp = qb + (size_t)bh * SEQ * HD;
    const unsigned short* Kp = kbuf + (size_t)bh * SEQ * HD;
    const unsigned short* Vp = vt + (size_t)bh * HD * SEQ;

    __shared__ unsigned short Plds[4][16 * 32];
    unsigned short* myP = Plds[wid];

    bhalf8 qf0, qf1;
    {
        const unsigned short* p = Qp + (size_t)(q0 + c16) * HD + g * 8;
        qf0 = *(const bhalf8*)p;
        qf1 = *(const bhalf8*)(p + 32);
    }
    fvec4 acc[4];
#pragma unroll
    for (int i = 0; i < 4; ++i) acc[i] = zero4();
    float mrow[4] = {-1e30f, -1e30f, -1e30f, -1e30f};
    float srow[4] = {0.f, 0.f, 0.f, 0.f};

    int kstart = q0 - W2; if (kstart < 0) kstart = 0; kstart &= ~31;
    int kend = q0 + 15 + W2; if (kend > SEQ - 1) kend = SEQ - 1;

    for (int t0 = kstart; t0 <= kend; t0 += 32) {
        fvec4 sc0 = zero4(), sc1 = zero4();
        {
            const unsigned short* kp = Kp + (size_t)(t0 + c16) * HD + g * 8;
            bhalf8 ka = *(const bhalf8*)kp;
            bhalf8 kb2 = *(const bhalf8*)(kp + 32);
            sc0 = __builtin_amdgcn_mfma_f32_16x16x32_bf16(qf0, ka, sc0, 0, 0, 0);
            sc0 = __builtin_amdgcn_mfma_f32_16x16x32_bf16(qf1, kb2, sc0, 0, 0, 0);
        }
        {
            const unsigned short* kp = Kp + (size_t)(t0 + 16 + c16) * HD + g * 8;
            bhalf8 ka = *(const bhalf8*)kp;
            bhalf8 kb2 = *(const bhalf8*)(kp + 32);
            sc1 = __builtin_amdgcn_mfma_f32_16x16x32_bf16(qf0, ka, sc1, 0, 0, 0);
            sc1 = __builtin_amdgcn_mfma_f32_16x16x32_bf16(qf1, kb2, sc1, 0, 0, 0);
        }
        // band mask
#pragma unroll
        for (int r = 0; r < 4; ++r) {
            int ia = q0 + 4 * g + r;
            int j0 = t0 + c16, j1 = t0 + 16 + c16;
            if (j0 < ia - W2 || j0 > ia + W2) sc0[r] = -1e30f;
            if (j1 < ia - W2 || j1 > ia + W2) sc1[r] = -1e30f;
        }
        // online softmax update
#pragma unroll
        for (int r = 0; r < 4; ++r) {
            float pm = rowmax16(fmaxf(sc0[r], sc1[r]));
            float mn = fmaxf(mrow[r], pm);
            float f = __expf(mrow[r] - mn);
            mrow[r] = mn;
            float p0 = __expf(sc0[r] - mn);
            float p1 = __expf(sc1[r] - mn);
            srow[r] = srow[r] * f + (p0 + p1);   // per-lane partial; reduced at end
#pragma unroll
            for (int db = 0; db < 4; ++db) acc[db][r] *= f;
            myP[(4 * g + r) * 32 + c16] = f2bf(p0);
            myP[(4 * g + r) * 32 + 16 + c16] = f2bf(p1);
        }
        asm volatile("s_waitcnt lgkmcnt(0)" ::: "memory");
        __builtin_amdgcn_sched_barrier(0);
        bhalf8 pf = *(const bhalf8*)(myP + c16 * 32 + g * 8);
#pragma unroll
        for (int db = 0; db < 4; ++db) {
            const unsigned short* vp = Vp + (size_t)(db * 16 + c16) * SEQ + t0 + g * 8;
            bhalf8 vf = *(const bhalf8*)vp;
            acc[db] = __builtin_amdgcn_mfma_f32_16x16x32_bf16(pf, vf, acc[db], 0, 0, 0);
        }
    }

    float inv[4];
#pragma unroll
    for (int r = 0; r < 4; ++r) inv[r] = 1.f / rowsum16(srow[r]);

    const int b = bh >> 4, h = bh & 15;
#pragma unroll
    for (int db = 0; db < 4; ++db)
#pragma unroll
        for (int r = 0; r < 4; ++r) {
            int si = q0 + 4 * g + r;
            attn[((size_t)(b * SEQ) + si) * HID + h * HD + db * 16 + c16] =
                f2bf(acc[db][r] * inv[r]);
        }
}

// ---------------- launch ----------------

extern "C" void kernel_launch(void* const* d_in, const int* in_sizes, int n_in,
                              void* d_out, int out_size, void* d_ws, size_t ws_size,
                              hipStream_t stream) {
    const float* x  = (const float*)d_in[0];
    const float* wq = (const float*)d_in[1];
    const float* bq = (const float*)d_in[2];
    const float* wk = (const float*)d_in[3];
    const float* bk = (const float*)d_in[4];
    const float* wv = (const float*)d_in[5];
    const float* bv = (const float*)d_in[6];
    const float* wo = (const float*)d_in[7];
    const float* bo = (const float*)d_in[8];
    float* out = (float*)d_out;

    char* ws = (char*)d_ws;
    // layout (bytes): xb 8MB | wqt,wkt,wvt,wot 2MB each | qb 8MB | kb 8MB | vt 8MB | attn 8MB
    unsigned short* xb   = (unsigned short*)(ws);
    unsigned short* wqt  = (unsigned short*)(ws + (8u << 20));
    unsigned short* wkt  = wqt + 1024 * 1024;
    unsigned short* wvt  = wkt + 1024 * 1024;
    unsigned short* wot  = wvt + 1024 * 1024;
    unsigned short* qb   = wot + 1024 * 1024;
    unsigned short* kbuf = qb + 4u * 1024 * 1024;
    unsigned short* vt   = kbuf + 4u * 1024 * 1024;
    unsigned short* attn = vt + 4u * 1024 * 1024;

    k_convert_x<<<dim3(2048), dim3(256), 0, stream>>>(x, xb);
    k_transpose_w<<<dim3(32, 32, 4), dim3(32, 8), 0, stream>>>(wq, wk, wv, wo,
                                                               wqt, wkt, wvt, wot);
    k_gemm_qkv<<<dim3(8, 32, 3), dim3(512), 0, stream>>>(xb, wqt, wkt, wvt,
                                                         bq, bk, bv, qb, kbuf, vt);
    k_attn<<<dim3(SEQ / 64, BATCH * NH), dim3(256), 0, stream>>>(qb, kbuf, vt, attn);
    k_gemm_out<<<dim3(8, 32), dim3(512), 0, stream>>>(attn, wot, bo, out);
}

// Round 11
// 177.388 us; speedup vs baseline: 1.0866x; 1.0172x over previous
//
#include <hip/hip_runtime.h>
#include <hip/hip_bf16.h>
#include <stdint.h>

#define BATCH 2
#define SEQ   2048
#define HID   1024
#define NH    16
#define HD    64
#define W2    128   // WINDOW/2

using bhalf8 = __attribute__((ext_vector_type(8))) short;
using fvec4  = __attribute__((ext_vector_type(4))) float;
using u16x8  = __attribute__((ext_vector_type(8))) unsigned short;

__device__ __forceinline__ unsigned short f2bf(float f) {
    union { float f; unsigned int u; } c; c.f = f;
    unsigned int u = c.u;
    u += 0x7FFFu + ((u >> 16) & 1u);   // RNE
    return (unsigned short)(u >> 16);
}

__device__ __forceinline__ fvec4 zero4() {
    fvec4 z = {0.f, 0.f, 0.f, 0.f};
    return z;
}

__device__ __forceinline__ void load_lds16(const void* g, void* l) {
    __builtin_amdgcn_global_load_lds(
        (const __attribute__((address_space(1))) void*)g,
        (__attribute__((address_space(3))) void*)l, 16, 0, 0);
}

// ---------------- conversion kernels ----------------

__global__ __launch_bounds__(256) void k_convert_x(const float* __restrict__ x,
                                                   unsigned short* __restrict__ xb) {
    int i = (blockIdx.x * 256 + threadIdx.x) * 8;
    float4 a = *(const float4*)(x + i);
    float4 b = *(const float4*)(x + i + 4);
    u16x8 o;
    o[0] = f2bf(a.x); o[1] = f2bf(a.y); o[2] = f2bf(a.z); o[3] = f2bf(a.w);
    o[4] = f2bf(b.x); o[5] = f2bf(b.y); o[6] = f2bf(b.z); o[7] = f2bf(b.w);
    *(u16x8*)(xb + i) = o;
}

// transpose [K][N] fp32 -> [N][K] bf16, 32x32 tiles
__global__ __launch_bounds__(256) void k_transpose_w(
    const float* __restrict__ w0, const float* __restrict__ w1,
    const float* __restrict__ w2, const float* __restrict__ w3,
    unsigned short* __restrict__ t0, unsigned short* __restrict__ t1,
    unsigned short* __restrict__ t2, unsigned short* __restrict__ t3) {
    int z = blockIdx.z;
    const float* src = (z == 0) ? w0 : (z == 1) ? w1 : (z == 2) ? w2 : w3;
    unsigned short* dst = (z == 0) ? t0 : (z == 1) ? t1 : (z == 2) ? t2 : t3;
    __shared__ float tile[32][33];
    int n0 = blockIdx.x * 32, k0 = blockIdx.y * 32;
    int tx = threadIdx.x, ty = threadIdx.y;
#pragma unroll
    for (int r = 0; r < 4; ++r)
        tile[ty + 8 * r][tx] = src[(size_t)(k0 + ty + 8 * r) * HID + n0 + tx];
    __syncthreads();
#pragma unroll
    for (int r = 0; r < 4; ++r)
        dst[(size_t)(n0 + ty + 8 * r) * HID + k0 + tx] = f2bf(tile[tx][ty + 8 * r]);
}

// ---------------- GEMM mainloop ----------------
// 128x128 tile, BK=64, 8 waves (512 threads, wave grid 2M x 4N, acc[4][2]),
// 2-deep LDS double-buffer, vmcnt(0)+barrier then stage-next then compute.
// LDS granule XOR-swizzle: granule ^= row&7; source pre-swizzled so the
// global_load_lds dest stays linear (bank conflicts measured 0 in R5).
// T5 setprio around the MFMA cluster.

__device__ __forceinline__ void stage_tile64(const unsigned short* __restrict__ A,
                                             const unsigned short* __restrict__ Bt,
                                             int m0, int n0, int k0,
                                             unsigned short* As, unsigned short* Bs,
                                             int t) {
#pragma unroll
    for (int i = 0; i < 2; ++i) {
        int chunk = t + 512 * i;           // 1024 chunks of 16 B per matrix
        int row = chunk >> 3, ch = chunk & 7;
        int chs = ch ^ (row & 7);          // inverse-swizzle the source granule
        load_lds16(A + (size_t)(m0 + row) * HID + k0 + chs * 8, As + chunk * 8);
        load_lds16(Bt + (size_t)(n0 + row) * HID + k0 + chs * 8, Bs + chunk * 8);
    }
}

__device__ __forceinline__ void gemm_tile8(const unsigned short* __restrict__ A,
                                           const unsigned short* __restrict__ Bt,
                                           int m0, int n0,
                                           unsigned short* As, unsigned short* Bs,
                                           fvec4 acc[4][2]) {
    const int t = threadIdx.x;
    const int lane = t & 63;
    const int wid = t >> 6;
    const int wr = wid >> 2, wc = wid & 3;
    const int c16 = lane & 15, g = lane >> 4;

#pragma unroll
    for (int mi = 0; mi < 4; ++mi)
#pragma unroll
        for (int ni = 0; ni < 2; ++ni) acc[mi][ni] = zero4();

    stage_tile64(A, Bt, m0, n0, 0, As, Bs, t);

    int cur = 0;
    for (int k0 = 0; k0 < HID; k0 += 64) {
        asm volatile("s_waitcnt vmcnt(0)" ::: "memory");
        __builtin_amdgcn_sched_barrier(0);
        __builtin_amdgcn_s_barrier();

        if (k0 + 64 < HID)
            stage_tile64(A, Bt, m0, n0, k0 + 64,
                         As + (cur ^ 1) * 8192, Bs + (cur ^ 1) * 8192, t);

        const unsigned short* Ab = As + cur * 8192;
        const unsigned short* Bb = Bs + cur * 8192;
        bhalf8 af[2][4], bf[2][2];
#pragma unroll
        for (int ks = 0; ks < 2; ++ks) {
#pragma unroll
            for (int i = 0; i < 4; ++i) {
                int ra = wr * 64 + i * 16 + c16;
                af[ks][i] = *(const bhalf8*)(Ab + ra * 64 + ((4 * ks + g) ^ (ra & 7)) * 8);
            }
#pragma unroll
            for (int i = 0; i < 2; ++i) {
                int rb = wc * 32 + i * 16 + c16;
                bf[ks][i] = *(const bhalf8*)(Bb + rb * 64 + ((4 * ks + g) ^ (rb & 7)) * 8);
            }
        }
        __builtin_amdgcn_s_setprio(1);
#pragma unroll
        for (int ks = 0; ks < 2; ++ks)
#pragma unroll
            for (int mi = 0; mi < 4; ++mi)
#pragma unroll
                for (int ni = 0; ni < 2; ++ni)
                    acc[mi][ni] = __builtin_amdgcn_mfma_f32_16x16x32_bf16(
                        af[ks][mi], bf[ks][ni], acc[mi][ni], 0, 0, 0);
        __builtin_amdgcn_s_setprio(0);
        cur ^= 1;
    }
}

// QKV projection: z=0 -> Q (scaled, [b,h,s,d]), z=1 -> K ([b,h,s,d]), z=2 -> V^T ([b,h,d,s])
__global__ __launch_bounds__(512, 4) void k_gemm_qkv(
    const unsigned short* __restrict__ xb,
    const unsigned short* __restrict__ wqt, const unsigned short* __restrict__ wkt,
    const unsigned short* __restrict__ wvt,
    const float* __restrict__ bq, const float* __restrict__ bk, const float* __restrict__ bv,
    unsigned short* __restrict__ qb, unsigned short* __restrict__ kbuf,
    unsigned short* __restrict__ vt) {
    __shared__ unsigned short SH[2][2 * 128 * 64];   // As dbuf | Bs dbuf (64 KB)
    const int z = blockIdx.z;
    const unsigned short* Bt = (z == 0) ? wqt : (z == 1) ? wkt : wvt;
    const float* bias = (z == 0) ? bq : (z == 1) ? bk : bv;
    const int m0 = blockIdx.y * 128, n0 = blockIdx.x * 128;
    fvec4 acc[4][2];
    gemm_tile8(xb, Bt, m0, n0, SH[0], SH[1], acc);

    const int t = threadIdx.x, lane = t & 63, wid = t >> 6;
    const int wr = wid >> 2, wc = wid & 3, c16 = lane & 15, g = lane >> 4;

    if (z != 2) {
#pragma unroll
        for (int mi = 0; mi < 4; ++mi) {
#pragma unroll
            for (int ni = 0; ni < 2; ++ni) {
                int gcol = n0 + wc * 32 + ni * 16 + c16;
                int h = gcol >> 6, d = gcol & 63;
                float bsv = bias[gcol];
#pragma unroll
                for (int r = 0; r < 4; ++r) {
                    int grow = m0 + wr * 64 + mi * 16 + 4 * g + r;
                    int b = grow >> 11, s = grow & (SEQ - 1);
                    float v = acc[mi][ni][r] + bsv;
                    if (z == 0)
                        qb[((size_t)(b * NH + h) * SEQ + s) * HD + d] = f2bf(v * 0.125f);
                    else
                        kbuf[((size_t)(b * NH + h) * SEQ + s) * HD + d] = f2bf(v);
                }
            }
        }
    } else {
        // V^T: transpose through LDS, store coalesced along s.
        unsigned short* VL = &SH[0][0];   // 128 x 132 (padded), 33 KB
        __syncthreads();                  // everyone done reading staging buffers
#pragma unroll
        for (int mi = 0; mi < 4; ++mi)
#pragma unroll
            for (int ni = 0; ni < 2; ++ni) {
                int dl = wc * 32 + ni * 16 + c16;
                float bsv = bias[n0 + dl];
#pragma unroll
                for (int r = 0; r < 4; ++r) {
                    int sl = wr * 64 + mi * 16 + 4 * g + r;
                    VL[dl * 132 + sl] = f2bf(acc[mi][ni][r] + bsv);
                }
            }
        __syncthreads();
        const int b = m0 >> 11, sbase = m0 & (SEQ - 1);
#pragma unroll
        for (int it = 0; it < 4; ++it) {
            int slot = t + 512 * it;
            int dl = slot >> 4, ch = slot & 15;
            int gcol = n0 + dl;
            int h = gcol >> 6, d = gcol & 63;
            u16x8 v = *(const u16x8*)(VL + dl * 132 + ch * 8);
            *(u16x8*)(vt + ((size_t)(b * NH + h) * HD + d) * SEQ + sbase + ch * 8) = v;
        }
    }
}

// Output projection -> fp32 out
__global__ __launch_bounds__(512, 4) void k_gemm_out(
    const unsigned short* __restrict__ attn, const unsigned short* __restrict__ wot,
    const float* __restrict__ bo, float* __restrict__ out) {
    __shared__ unsigned short SH[2][2 * 128 * 64];
    const int m0 = blockIdx.y * 128, n0 = blockIdx.x * 128;
    fvec4 acc[4][2];
    gemm_tile8(attn, wot, m0, n0, SH[0], SH[1], acc);

    const int lane = threadIdx.x & 63, wid = threadIdx.x >> 6;
    const int wr = wid >> 2, wc = wid & 3, c16 = lane & 15, g = lane >> 4;
#pragma unroll
    for (int mi = 0; mi < 4; ++mi) {
#pragma unroll
        for (int ni = 0; ni < 2; ++ni) {
            int gcol = n0 + wc * 32 + ni * 16 + c16;
            float bsv = bo[gcol];
#pragma unroll
            for (int r = 0; r < 4; ++r) {
                int grow = m0 + wr * 64 + mi * 16 + 4 * g + r;
                out[(size_t)grow * HID + gcol] = acc[mi][ni][r] + bsv;
            }
        }
    }
}

// ---------------- windowed flash attention (swapped-operand, in-register P) ----
// grid: (SEQ/64, BATCH*NH), block 256. Each wave: 16 query COLUMNS.
// S^T = mfma(K, Q): lane (g,c16) holds S[key=t0+4g+r][q=q0+c16] — softmax
// over keys is 7 fmax + 2 shfl_xor (columns live across 4 lanes 16 apart).
// P^T stays in registers; B-fragment for PV built with 8 __shfl (no LDS,
// no lgkmcnt drain, no sched_barrier -> QK(i+1) can overlap PV(i)).
// O^T = mfma(V^T, P^T): acc col=q, row=d.
__global__ __launch_bounds__(256) void k_attn(
    const unsigned short* __restrict__ qb, const unsigned short* __restrict__ kbuf,
    const unsigned short* __restrict__ vt, unsigned short* __restrict__ attn) {
    const int bh = blockIdx.y;
    const int wid = threadIdx.x >> 6, lane = threadIdx.x & 63;
    const int g = lane >> 4, c16 = lane & 15;
    const int q0 = blockIdx.x * 64 + wid * 16;

    const unsigned short* Qp = qb + (size_t)bh * SEQ * HD;
    const unsigned short* Kp = kbuf + (size_t)bh * SEQ * HD;
    const unsigned short* Vp = vt + (size_t)bh * HD * SEQ;

    // Q fragment: used as the B-operand of mfma(K,Q) (col = q = c16)
    bhalf8 qf0, qf1;
    {
        const unsigned short* p = Qp + (size_t)(q0 + c16) * HD + g * 8;
        qf0 = *(const bhalf8*)p;
        qf1 = *(const bhalf8*)(p + 32);
    }
    fvec4 acc[4];
#pragma unroll
    for (int i = 0; i < 4; ++i) acc[i] = zero4();
    float mq = -1e30f;   // running max for this lane's query column
    float sq = 0.f;      // per-lane partial denominator

    const int ia = q0 + c16;                    // my query index
    int kstart = q0 - W2; if (kstart < 0) kstart = 0; kstart &= ~31;
    int kend = q0 + 15 + W2; if (kend > SEQ - 1) kend = SEQ - 1;

    const int sl1 = ((2 * g) & 3) * 16 + c16;       // B-frag source lanes
    const int sl2 = ((2 * g + 1) & 3) * 16 + c16;

    for (int t0 = kstart; t0 <= kend; t0 += 32) {
        // S^T: keys t0+0..15 (st0) and t0+16..31 (st1), q = c16
        fvec4 st0 = zero4(), st1 = zero4();
        {
            const unsigned short* kp = Kp + (size_t)(t0 + c16) * HD + g * 8;
            bhalf8 ka = *(const bhalf8*)kp;
            bhalf8 ka2 = *(const bhalf8*)(kp + 32);
            st0 = __builtin_amdgcn_mfma_f32_16x16x32_bf16(ka, qf0, st0, 0, 0, 0);
            st0 = __builtin_amdgcn_mfma_f32_16x16x32_bf16(ka2, qf1, st0, 0, 0, 0);
        }
        {
            const unsigned short* kp = Kp + (size_t)(t0 + 16 + c16) * HD + g * 8;
            bhalf8 kb = *(const bhalf8*)kp;
            bhalf8 kb2 = *(const bhalf8*)(kp + 32);
            st1 = __builtin_amdgcn_mfma_f32_16x16x32_bf16(kb, qf0, st1, 0, 0, 0);
            st1 = __builtin_amdgcn_mfma_f32_16x16x32_bf16(kb2, qf1, st1, 0, 0, 0);
        }
        // band mask: row = key, my column = query ia
#pragma unroll
        for (int r = 0; r < 4; ++r) {
            int j0 = t0 + 4 * g + r, j1 = j0 + 16;
            if (j0 < ia - W2 || j0 > ia + W2) st0[r] = -1e30f;
            if (j1 < ia - W2 || j1 > ia + W2) st1[r] = -1e30f;
        }
        // column max across 8 regs + lanes {c16, c16+16, c16+32, c16+48}
        float pm = fmaxf(fmaxf(fmaxf(st0[0], st0[1]), fmaxf(st0[2], st0[3])),
                         fmaxf(fmaxf(st1[0], st1[1]), fmaxf(st1[2], st1[3])));
        pm = fmaxf(pm, __shfl_xor(pm, 16));
        pm = fmaxf(pm, __shfl_xor(pm, 32));
        float mn = fmaxf(mq, pm);
        float f = __expf(mq - mn);
        mq = mn;
        float p0[4], p1[4];
        float psum = 0.f;
#pragma unroll
        for (int r = 0; r < 4; ++r) {
            p0[r] = __expf(st0[r] - mn);
            p1[r] = __expf(st1[r] - mn);
            psum += p0[r] + p1[r];
        }
        sq = sq * f + psum;
#pragma unroll
        for (int db = 0; db < 4; ++db) acc[db] *= f;

        // pack P to bf16 pairs and redistribute into the PV B-fragment:
        // target lane (g,c16) needs keys t0+8g..t0+8g+7 of column c16
        unsigned int a01 = (unsigned int)f2bf(p0[0]) | ((unsigned int)f2bf(p0[1]) << 16);
        unsigned int a23 = (unsigned int)f2bf(p0[2]) | ((unsigned int)f2bf(p0[3]) << 16);
        unsigned int b01 = (unsigned int)f2bf(p1[0]) | ((unsigned int)f2bf(p1[1]) << 16);
        unsigned int b23 = (unsigned int)f2bf(p1[2]) | ((unsigned int)f2bf(p1[3]) << 16);
        unsigned int A01 = (unsigned int)__shfl((int)a01, sl1);
        unsigned int A23 = (unsigned int)__shfl((int)a23, sl1);
        unsigned int A01b = (unsigned int)__shfl((int)a01, sl2);
        unsigned int A23b = (unsigned int)__shfl((int)a23, sl2);
        unsigned int B01 = (unsigned int)__shfl((int)b01, sl1);
        unsigned int B23 = (unsigned int)__shfl((int)b23, sl1);
        unsigned int B01b = (unsigned int)__shfl((int)b01, sl2);
        unsigned int B23b = (unsigned int)__shfl((int)b23, sl2);
        union { unsigned int u[4]; bhalf8 v; } pb;
        pb.u[0] = (g < 2) ? A01 : B01;
        pb.u[1] = (g < 2) ? A23 : B23;
        pb.u[2] = (g < 2) ? A01b : B01b;
        pb.u[3] = (g < 2) ? A23b : B23b;

        // PV: O^T += V^T · P^T  (A = V^T rows d, B = P^T cols q)
#pragma unroll
        for (int db = 0; db < 4; ++db) {
            const unsigned short* vp = Vp + (size_t)(db * 16 + c16) * SEQ + t0 + g * 8;
            bhalf8 vf = *(const bhalf8*)vp;
            acc[db] = __builtin_amdgcn_mfma_f32_16x16x32_bf16(vf, pb.v, acc[db], 0, 0, 0);
        }
    }

    // denominator: reduce partials across the 4 lanes of this column
    sq += __shfl_xor(sq, 16);
    sq += __shfl_xor(sq, 32);
    float inv = 1.f / sq;

    const int b = bh >> 4, h = bh & 15;
    const int si = q0 + c16;
#pragma unroll
    for (int db = 0; db < 4; ++db)
#pragma unroll
        for (int r = 0; r < 4; ++r) {
            int d = db * 16 + 4 * g + r;
            attn[((size_t)(b * SEQ) + si) * HID + h * HD + d] = f2bf(acc[db][r] * inv);
        }
}

// ---------------- launch ----------------

extern "C" void kernel_launch(void* const* d_in, const int* in_sizes, int n_in,
                              void* d_out, int out_size, void* d_ws, size_t ws_size,
                              hipStream_t stream) {
    const float* x  = (const float*)d_in[0];
    const float* wq = (const float*)d_in[1];
    const float* bq = (const float*)d_in[2];
    const float* wk = (const float*)d_in[3];
    const float* bk = (const float*)d_in[4];
    const float* wv = (const float*)d_in[5];
    const float* bv = (const float*)d_in[6];
    const float* wo = (const float*)d_in[7];
    const float* bo = (const float*)d_in[8];
    float* out = (float*)d_out;

    char* ws = (char*)d_ws;
    // layout (bytes): xb 8MB | wqt,wkt,wvt,wot 2MB each | qb 8MB | kb 8MB | vt 8MB | attn 8MB
    unsigned short* xb   = (unsigned short*)(ws);
    unsigned short* wqt  = (unsigned short*)(ws + (8u << 20));
    unsigned short* wkt  = wqt + 1024 * 1024;
    unsigned short* wvt  = wkt + 1024 * 1024;
    unsigned short* wot  = wvt + 1024 * 1024;
    unsigned short* qb   = wot + 1024 * 1024;
    unsigned short* kbuf = qb + 4u * 1024 * 1024;
    unsigned short* vt   = kbuf + 4u * 1024 * 1024;
    unsigned short* attn = vt + 4u * 1024 * 1024;

    k_convert_x<<<dim3(2048), dim3(256), 0, stream>>>(x, xb);
    k_transpose_w<<<dim3(32, 32, 4), dim3(32, 8), 0, stream>>>(wq, wk, wv, wo,
                                                               wqt, wkt, wvt, wot);
    k_gemm_qkv<<<dim3(8, 32, 3), dim3(512), 0, stream>>>(xb, wqt, wkt, wvt,
                                                         bq, bk, bv, qb, kbuf, vt);
    k_attn<<<dim3(SEQ / 64, BATCH * NH), dim3(256), 0, stream>>>(qb, kbuf, vt, attn);
    k_gemm_out<<<dim3(8, 32), dim3(512), 0, stream>>>(attn, wot, bo, out);
}